// Round 1
// baseline (988.077 us; speedup 1.0000x reference)
//
#include <hip/hip_runtime.h>

#define NPTS 32768
#define CH 64
#define KNN 16
#define NE (NPTS*KNN)
#define EPS 1e-5f

// ---- workspace layout (float offsets) ----
#define OFF_BN1S 0
#define OFF_BN1Q 64
#define OFF_PS   128
#define OFF_PQ   132
#define OFF_W1S  192
#define OFF_W1Q  256
#define OFF_W2S  320
#define OFF_W2Q  328
#define OFF_BN2S 384
#define OFF_BN2Q 448
#define OFF_BN3S 512
#define OFF_BN3Q 576
#define OFF_T1   1024
#define SZ_NC    (NPTS*CH)
#define OFF_K    (OFF_T1 + SZ_NC)
#define OFF_Q    (OFF_K + SZ_NC)
#define OFF_V    (OFF_Q + SZ_NC)
#define OFF_A2   (OFF_V + SZ_NC)
#define OFF_OUT  (OFF_A2 + NE*8)
#define OFF_H3   (OFF_OUT + SZ_NC)

__device__ __forceinline__ float frelu(float x){ return fmaxf(x, 0.f); }

// [N,64] @ W[64,64]^T, optional input-side bn(sc,sh)+relu, output raw + per-channel sum/sumsq stats
__global__ __launch_bounds__(64) void k_gemm64(
    const float* __restrict__ in, const float* __restrict__ W,
    float* __restrict__ out,
    const float* __restrict__ bnsum, const float* __restrict__ bnsq,
    const float* __restrict__ bng, const float* __restrict__ bnb,
    int applyBn,
    float* __restrict__ osum, float* __restrict__ osq)
{
    __shared__ float Wl[CH*CH];
    __shared__ float sc[CH], sh[CH];
    const int tid = threadIdx.x;
    {
        const float4* W4 = (const float4*)W;
        float4* Wl4 = (float4*)Wl;
        #pragma unroll
        for (int i = 0; i < 16; ++i) Wl4[i*64 + tid] = W4[i*64 + tid];
    }
    if (applyBn && tid < CH) {
        float m = bnsum[tid] * (1.f/NPTS);
        float v = bnsq[tid] * (1.f/NPTS) - m*m;
        float s = bng[tid] * rsqrtf(v + EPS);
        sc[tid] = s; sh[tid] = bnb[tid] - m*s;
    }
    __syncthreads();

    const int row = blockIdx.x * 64 + tid;
    float xr[CH];
    {
        const float4* iv = (const float4*)(in + (size_t)row*CH);
        #pragma unroll
        for (int i = 0; i < 16; ++i) {
            float4 t = iv[i];
            xr[4*i+0]=t.x; xr[4*i+1]=t.y; xr[4*i+2]=t.z; xr[4*i+3]=t.w;
        }
    }
    if (applyBn) {
        #pragma unroll
        for (int i = 0; i < CH; ++i) xr[i] = frelu(xr[i]*sc[i] + sh[i]);
    }
    float4* ov = (float4*)(out + (size_t)row*CH);
    for (int cc = 0; cc < 16; ++cc) {
        float4 acc = make_float4(0,0,0,0);
        const float* w0 = &Wl[(cc*4+0)*CH];
        const float* w1 = &Wl[(cc*4+1)*CH];
        const float* w2 = &Wl[(cc*4+2)*CH];
        const float* w3 = &Wl[(cc*4+3)*CH];
        #pragma unroll
        for (int i = 0; i < CH; ++i) {
            float xv = xr[i];
            acc.x += xv*w0[i]; acc.y += xv*w1[i]; acc.z += xv*w2[i]; acc.w += xv*w3[i];
        }
        ov[cc] = acc;
        float4 sq = make_float4(acc.x*acc.x, acc.y*acc.y, acc.z*acc.z, acc.w*acc.w);
        #pragma unroll
        for (int m = 32; m >= 1; m >>= 1) {
            acc.x += __shfl_xor(acc.x, m); acc.y += __shfl_xor(acc.y, m);
            acc.z += __shfl_xor(acc.z, m); acc.w += __shfl_xor(acc.w, m);
            sq.x  += __shfl_xor(sq.x, m);  sq.y  += __shfl_xor(sq.y, m);
            sq.z  += __shfl_xor(sq.z, m);  sq.w  += __shfl_xor(sq.w, m);
        }
        if (tid == 0) {
            atomicAdd(&osum[cc*4+0], acc.x); atomicAdd(&osum[cc*4+1], acc.y);
            atomicAdd(&osum[cc*4+2], acc.z); atomicAdd(&osum[cc*4+3], acc.w);
            atomicAdd(&osq[cc*4+0], sq.x);  atomicAdd(&osq[cc*4+1], sq.y);
            atomicAdd(&osq[cc*4+2], sq.z);  atomicAdd(&osq[cc*4+3], sq.w);
        }
    }
}

// h = relu(bn1(t1)); k/q/v = h @ W{k,q,v}^T + b
__global__ __launch_bounds__(64) void k_kqv(
    const float* __restrict__ t1,
    const float* __restrict__ Wk, const float* __restrict__ bk,
    const float* __restrict__ Wq, const float* __restrict__ bq,
    const float* __restrict__ Wv, const float* __restrict__ bv,
    const float* __restrict__ bnsum, const float* __restrict__ bnsq,
    const float* __restrict__ bng, const float* __restrict__ bnb,
    float* __restrict__ kout, float* __restrict__ qout, float* __restrict__ vout)
{
    __shared__ float Wl[3*CH*CH];
    __shared__ float bias[3*CH];
    __shared__ float sc[CH], sh[CH];
    const int tid = threadIdx.x;
    {
        float4* Wl4 = (float4*)Wl;
        const float4* s0 = (const float4*)Wk;
        const float4* s1 = (const float4*)Wq;
        const float4* s2 = (const float4*)Wv;
        #pragma unroll
        for (int i = 0; i < 16; ++i) {
            Wl4[       i*64 + tid] = s0[i*64+tid];
            Wl4[1024 + i*64 + tid] = s1[i*64+tid];
            Wl4[2048 + i*64 + tid] = s2[i*64+tid];
        }
        bias[tid] = bk[tid]; bias[64+tid] = bq[tid]; bias[128+tid] = bv[tid];
        float m = bnsum[tid]*(1.f/NPTS);
        float v = bnsq[tid]*(1.f/NPTS) - m*m;
        float s = bng[tid]*rsqrtf(v+EPS);
        sc[tid]=s; sh[tid]=bnb[tid]-m*s;
    }
    __syncthreads();
    const int row = blockIdx.x*64 + tid;
    float h[CH];
    {
        const float4* iv = (const float4*)(t1 + (size_t)row*CH);
        #pragma unroll
        for (int i=0;i<16;++i){ float4 t = iv[i];
            h[4*i]=t.x; h[4*i+1]=t.y; h[4*i+2]=t.z; h[4*i+3]=t.w; }
    }
    #pragma unroll
    for (int i=0;i<CH;++i) h[i] = frelu(h[i]*sc[i]+sh[i]);

    float* outs[3] = {kout, qout, vout};
    for (int m = 0; m < 3; ++m) {
        float4* ov = (float4*)(outs[m] + (size_t)row*CH);
        const float* Wm = &Wl[m*CH*CH];
        const float* bm = &bias[m*CH];
        for (int cc = 0; cc < 16; ++cc) {
            float4 acc = make_float4(bm[cc*4], bm[cc*4+1], bm[cc*4+2], bm[cc*4+3]);
            const float* w0=&Wm[(cc*4+0)*CH];
            const float* w1=&Wm[(cc*4+1)*CH];
            const float* w2=&Wm[(cc*4+2)*CH];
            const float* w3=&Wm[(cc*4+3)*CH];
            #pragma unroll
            for (int i=0;i<CH;++i){ float xv=h[i];
                acc.x+=xv*w0[i]; acc.y+=xv*w1[i]; acc.z+=xv*w2[i]; acc.w+=xv*w3[i]; }
            ov[cc]=acc;
        }
    }
}

// stats of u = rel @ p1_w^T + p1_b over E, 3 channels
__global__ __launch_bounds__(256) void k_pstats(
    const float* __restrict__ pos, const int* __restrict__ esrc,
    const float* __restrict__ p1w, const float* __restrict__ p1b,
    float* __restrict__ osum, float* __restrict__ osq)
{
    __shared__ float st[6];
    const int tid = threadIdx.x;
    if (tid < 6) st[tid] = 0.f;
    float w[9], b3[3];
    #pragma unroll
    for (int i=0;i<9;++i) w[i]=p1w[i];
    b3[0]=p1b[0]; b3[1]=p1b[1]; b3[2]=p1b[2];
    __syncthreads();
    float ls0=0,ls1=0,ls2=0,lq0=0,lq1=0,lq2=0;
    for (int e = blockIdx.x*blockDim.x + tid; e < NE; e += gridDim.x*blockDim.x) {
        int sj = esrc[e]; int d = e >> 4;
        float rx = pos[3*sj]-pos[3*d], ry = pos[3*sj+1]-pos[3*d+1], rz = pos[3*sj+2]-pos[3*d+2];
        float u0 = w[0]*rx + w[1]*ry + w[2]*rz + b3[0];
        float u1 = w[3]*rx + w[4]*ry + w[5]*rz + b3[1];
        float u2 = w[6]*rx + w[7]*ry + w[8]*rz + b3[2];
        ls0+=u0; ls1+=u1; ls2+=u2; lq0+=u0*u0; lq1+=u1*u1; lq2+=u2*u2;
    }
    #pragma unroll
    for (int m=32;m>=1;m>>=1){
        ls0+=__shfl_xor(ls0,m); ls1+=__shfl_xor(ls1,m); ls2+=__shfl_xor(ls2,m);
        lq0+=__shfl_xor(lq0,m); lq1+=__shfl_xor(lq1,m); lq2+=__shfl_xor(lq2,m);
    }
    if ((tid & 63) == 0) {
        atomicAdd(&st[0], ls0); atomicAdd(&st[1], ls1); atomicAdd(&st[2], ls2);
        atomicAdd(&st[3], lq0); atomicAdd(&st[4], lq1); atomicAdd(&st[5], lq2);
    }
    __syncthreads();
    if (tid < 3) { atomicAdd(&osum[tid], st[tid]); atomicAdd(&osq[tid], st[3+tid]); }
}

// apre = k[src]-q[dst]+delta ; stats over E, 64 channels
__global__ __launch_bounds__(256) void k_edge1(
    const float* __restrict__ pos, const int* __restrict__ esrc,
    const float* __restrict__ kbuf, const float* __restrict__ qbuf,
    const float* __restrict__ p1w, const float* __restrict__ p1b,
    const float* __restrict__ pg, const float* __restrict__ pb,
    const float* __restrict__ p2w, const float* __restrict__ p2b,
    const float* __restrict__ psum, const float* __restrict__ psq,
    float* __restrict__ osum, float* __restrict__ osq)
{
    __shared__ float sp2w[192], sp2b[64];
    __shared__ float acc[128];
    __shared__ float scp[3], shp[3];
    const int tid = threadIdx.x;
    if (tid < 192) sp2w[tid] = p2w[tid];
    if (tid < 64) sp2b[tid] = p2b[tid];
    if (tid < 128) acc[tid] = 0.f;
    if (tid < 3) {
        float m = psum[tid]*(1.f/NE);
        float v = psq[tid]*(1.f/NE) - m*m;
        float s = pg[tid]*rsqrtf(v+EPS);
        scp[tid]=s; shp[tid]=pb[tid]-m*s;
    }
    float pw[9], pbv[3];
    #pragma unroll
    for (int j=0;j<9;++j) pw[j]=p1w[j];
    pbv[0]=p1b[0]; pbv[1]=p1b[1]; pbv[2]=p1b[2];
    __syncthreads();
    const int lane = tid & 63;
    for (int e = blockIdx.x*blockDim.x + tid; e < NE; e += gridDim.x*blockDim.x) {
        const int sj = esrc[e]; const int d = e >> 4;
        const float rx = pos[3*sj]-pos[3*d], ry = pos[3*sj+1]-pos[3*d+1], rz = pos[3*sj+2]-pos[3*d+2];
        const float r0 = frelu((pw[0]*rx+pw[1]*ry+pw[2]*rz+pbv[0])*scp[0]+shp[0]);
        const float r1 = frelu((pw[3]*rx+pw[4]*ry+pw[5]*rz+pbv[1])*scp[1]+shp[1]);
        const float r2 = frelu((pw[6]*rx+pw[7]*ry+pw[8]*rz+pbv[2])*scp[2]+shp[2]);
        const float4* kv = (const float4*)(kbuf + (size_t)sj*CH);
        const float4* qv = (const float4*)(qbuf + (size_t)d*CH);
        for (int cc = 0; cc < 16; ++cc) {
            float4 k4 = kv[cc], q4 = qv[cc];
            const int c0 = cc*4;
            float a0 = k4.x - q4.x + r0*sp2w[(c0+0)*3]+r1*sp2w[(c0+0)*3+1]+r2*sp2w[(c0+0)*3+2]+sp2b[c0+0];
            float a1 = k4.y - q4.y + r0*sp2w[(c0+1)*3]+r1*sp2w[(c0+1)*3+1]+r2*sp2w[(c0+1)*3+2]+sp2b[c0+1];
            float a2 = k4.z - q4.z + r0*sp2w[(c0+2)*3]+r1*sp2w[(c0+2)*3+1]+r2*sp2w[(c0+2)*3+2]+sp2b[c0+2];
            float a3 = k4.w - q4.w + r0*sp2w[(c0+3)*3]+r1*sp2w[(c0+3)*3+1]+r2*sp2w[(c0+3)*3+2]+sp2b[c0+3];
            float q0=a0*a0, q1=a1*a1, q2=a2*a2, q3=a3*a3;
            #pragma unroll
            for (int m=32;m>=1;m>>=1){
                a0+=__shfl_xor(a0,m); a1+=__shfl_xor(a1,m); a2+=__shfl_xor(a2,m); a3+=__shfl_xor(a3,m);
                q0+=__shfl_xor(q0,m); q1+=__shfl_xor(q1,m); q2+=__shfl_xor(q2,m); q3+=__shfl_xor(q3,m);
            }
            if (lane == 0) {
                atomicAdd(&acc[c0+0],a0); atomicAdd(&acc[c0+1],a1);
                atomicAdd(&acc[c0+2],a2); atomicAdd(&acc[c0+3],a3);
                atomicAdd(&acc[64+c0+0],q0); atomicAdd(&acc[64+c0+1],q1);
                atomicAdd(&acc[64+c0+2],q2); atomicAdd(&acc[64+c0+3],q3);
            }
        }
    }
    __syncthreads();
    if (tid < 64) atomicAdd(&osum[tid], acc[tid]);
    else if (tid < 128) atomicAdd(&osq[tid-64], acc[tid]);
}

// a2 = relu(bn_w1(apre)) @ w1^T + b1 ; store a2 ; stats over E, 8 channels
__global__ __launch_bounds__(256) void k_edge2(
    const float* __restrict__ pos, const int* __restrict__ esrc,
    const float* __restrict__ kbuf, const float* __restrict__ qbuf,
    const float* __restrict__ p1w, const float* __restrict__ p1b,
    const float* __restrict__ pg, const float* __restrict__ pb,
    const float* __restrict__ p2w, const float* __restrict__ p2b,
    const float* __restrict__ psum, const float* __restrict__ psq,
    const float* __restrict__ w1sum, const float* __restrict__ w1sq,
    const float* __restrict__ w1g, const float* __restrict__ w1bn_b,
    const float* __restrict__ w1w, const float* __restrict__ w1bias,
    float* __restrict__ a2out,
    float* __restrict__ osum, float* __restrict__ osq)
{
    __shared__ float sp2w[192], sp2b[64], sw1[512];
    __shared__ float sc1[64], sh1[64];
    __shared__ float sw1b[8];
    __shared__ float acc[16];
    __shared__ float scp[3], shp[3];
    const int tid = threadIdx.x;
    if (tid < 192) sp2w[tid] = p2w[tid];
    if (tid < 64) {
        sp2b[tid] = p2b[tid];
        float m = w1sum[tid]*(1.f/NE);
        float v = w1sq[tid]*(1.f/NE) - m*m;
        float s = w1g[tid]*rsqrtf(v+EPS);
        sc1[tid]=s; sh1[tid]=w1bn_b[tid]-m*s;
    }
    sw1[tid] = w1w[tid]; sw1[256+tid] = w1w[256+tid];
    if (tid < 8) sw1b[tid] = w1bias[tid];
    if (tid < 16) acc[tid] = 0.f;
    if (tid < 3) {
        float m = psum[tid]*(1.f/NE);
        float v = psq[tid]*(1.f/NE) - m*m;
        float s = pg[tid]*rsqrtf(v+EPS);
        scp[tid]=s; shp[tid]=pb[tid]-m*s;
    }
    float pw[9], pbv[3];
    #pragma unroll
    for (int j=0;j<9;++j) pw[j]=p1w[j];
    pbv[0]=p1b[0]; pbv[1]=p1b[1]; pbv[2]=p1b[2];
    __syncthreads();
    const int lane = tid & 63;
    for (int e = blockIdx.x*blockDim.x + tid; e < NE; e += gridDim.x*blockDim.x) {
        const int sj = esrc[e]; const int d = e >> 4;
        const float rx = pos[3*sj]-pos[3*d], ry = pos[3*sj+1]-pos[3*d+1], rz = pos[3*sj+2]-pos[3*d+2];
        const float r0 = frelu((pw[0]*rx+pw[1]*ry+pw[2]*rz+pbv[0])*scp[0]+shp[0]);
        const float r1 = frelu((pw[3]*rx+pw[4]*ry+pw[5]*rz+pbv[1])*scp[1]+shp[1]);
        const float r2 = frelu((pw[6]*rx+pw[7]*ry+pw[8]*rz+pbv[2])*scp[2]+shp[2]);
        const float4* kv = (const float4*)(kbuf + (size_t)sj*CH);
        const float4* qv = (const float4*)(qbuf + (size_t)d*CH);
        float a2a[8];
        #pragma unroll
        for (int j=0;j<8;++j) a2a[j] = sw1b[j];
        for (int cc=0; cc<16; ++cc) {
            float4 k4 = kv[cc], q4 = qv[cc];
            const int c0 = cc*4;
            float b0 = frelu((k4.x - q4.x + r0*sp2w[(c0+0)*3]+r1*sp2w[(c0+0)*3+1]+r2*sp2w[(c0+0)*3+2]+sp2b[c0+0])*sc1[c0+0]+sh1[c0+0]);
            float b1 = frelu((k4.y - q4.y + r0*sp2w[(c0+1)*3]+r1*sp2w[(c0+1)*3+1]+r2*sp2w[(c0+1)*3+2]+sp2b[c0+1])*sc1[c0+1]+sh1[c0+1]);
            float b2 = frelu((k4.z - q4.z + r0*sp2w[(c0+2)*3]+r1*sp2w[(c0+2)*3+1]+r2*sp2w[(c0+2)*3+2]+sp2b[c0+2])*sc1[c0+2]+sh1[c0+2]);
            float b3 = frelu((k4.w - q4.w + r0*sp2w[(c0+3)*3]+r1*sp2w[(c0+3)*3+1]+r2*sp2w[(c0+3)*3+2]+sp2b[c0+3])*sc1[c0+3]+sh1[c0+3]);
            #pragma unroll
            for (int j=0;j<8;++j)
                a2a[j] += b0*sw1[j*64+c0] + b1*sw1[j*64+c0+1] + b2*sw1[j*64+c0+2] + b3*sw1[j*64+c0+3];
        }
        float4* a2v = (float4*)(a2out + (size_t)e*8);
        a2v[0] = make_float4(a2a[0],a2a[1],a2a[2],a2a[3]);
        a2v[1] = make_float4(a2a[4],a2a[5],a2a[6],a2a[7]);
        float qv8[8];
        #pragma unroll
        for (int j=0;j<8;++j) qv8[j]=a2a[j]*a2a[j];
        #pragma unroll
        for (int m=32;m>=1;m>>=1){
            #pragma unroll
            for (int j=0;j<8;++j){ a2a[j]+=__shfl_xor(a2a[j],m); qv8[j]+=__shfl_xor(qv8[j],m); }
        }
        if (lane == 0) {
            #pragma unroll
            for (int j=0;j<8;++j){ atomicAdd(&acc[j], a2a[j]); atomicAdd(&acc[8+j], qv8[j]); }
        }
    }
    __syncthreads();
    if (tid < 8) atomicAdd(&osum[tid], acc[tid]);
    else if (tid < 16) atomicAdd(&osq[tid-8], acc[tid]);
}

// a3 = relu(bn_w2(a2)) @ w2^T + b2 ; 16-edge softmax ; out = sum attn*(v[src]+delta)
__global__ __launch_bounds__(256) void k_attn(
    const float* __restrict__ pos, const int* __restrict__ esrc,
    const float* __restrict__ vbuf, const float* __restrict__ a2buf,
    const float* __restrict__ p1w, const float* __restrict__ p1b,
    const float* __restrict__ pg, const float* __restrict__ pb,
    const float* __restrict__ p2w, const float* __restrict__ p2b,
    const float* __restrict__ psum, const float* __restrict__ psq,
    const float* __restrict__ w2sum, const float* __restrict__ w2sq,
    const float* __restrict__ w2g, const float* __restrict__ w2bn_b,
    const float* __restrict__ w2w, const float* __restrict__ w2bias,
    float* __restrict__ outbuf)
{
    __shared__ float sp2w[192], sp2b[64], sw2[64];
    __shared__ float sw2b[8], sc2[8], sh2[8];
    __shared__ float scp[3], shp[3];
    const int tid = threadIdx.x;
    if (tid < 192) sp2w[tid] = p2w[tid];
    if (tid < 64) { sp2b[tid] = p2b[tid]; sw2[tid] = w2w[tid]; }
    if (tid < 8) {
        sw2b[tid] = w2bias[tid];
        float m = w2sum[tid]*(1.f/NE);
        float v = w2sq[tid]*(1.f/NE) - m*m;
        float s = w2g[tid]*rsqrtf(v+EPS);
        sc2[tid]=s; sh2[tid]=w2bn_b[tid]-m*s;
    }
    if (tid < 3) {
        float m = psum[tid]*(1.f/NE);
        float v = psq[tid]*(1.f/NE) - m*m;
        float s = pg[tid]*rsqrtf(v+EPS);
        scp[tid]=s; shp[tid]=pb[tid]-m*s;
    }
    float pw[9], pbv[3];
    #pragma unroll
    for (int j=0;j<9;++j) pw[j]=p1w[j];
    pbv[0]=p1b[0]; pbv[1]=p1b[1]; pbv[2]=p1b[2];
    __syncthreads();

    const int t = tid & 15;                  // edge slot within neighborhood
    const int i = blockIdx.x*16 + (tid>>4);  // target point
    const int e = i*KNN + t;
    const int sj = esrc[e];

    // attention logits
    const float4* a2v = (const float4*)a2buf;
    float4 aA = a2v[(size_t)e*2], aB = a2v[(size_t)e*2+1];
    float bb[8];
    bb[0]=frelu(aA.x*sc2[0]+sh2[0]); bb[1]=frelu(aA.y*sc2[1]+sh2[1]);
    bb[2]=frelu(aA.z*sc2[2]+sh2[2]); bb[3]=frelu(aA.w*sc2[3]+sh2[3]);
    bb[4]=frelu(aB.x*sc2[4]+sh2[4]); bb[5]=frelu(aB.y*sc2[5]+sh2[5]);
    bb[6]=frelu(aB.z*sc2[6]+sh2[6]); bb[7]=frelu(aB.w*sc2[7]+sh2[7]);
    float attn[8];
    #pragma unroll
    for (int s=0;s<8;++s){
        float a3 = sw2b[s];
        #pragma unroll
        for (int u=0;u<8;++u) a3 += bb[u]*sw2[s*8+u];
        attn[s]=a3;
    }
    // softmax over the 16-lane group, per channel s
    #pragma unroll
    for (int s=0;s<8;++s){
        float m = attn[s];
        #pragma unroll
        for (int msk=8;msk>=1;msk>>=1) m = fmaxf(m, __shfl_xor(m,msk));
        float p = __expf(attn[s]-m);
        float ssm = p;
        #pragma unroll
        for (int msk=8;msk>=1;msk>>=1) ssm += __shfl_xor(ssm,msk);
        attn[s] = p/ssm;
    }
    // delta recompute + weighted value aggregation
    const int d = i;
    const float rx = pos[3*sj]-pos[3*d], ry = pos[3*sj+1]-pos[3*d+1], rz = pos[3*sj+2]-pos[3*d+2];
    const float r0 = frelu((pw[0]*rx+pw[1]*ry+pw[2]*rz+pbv[0])*scp[0]+shp[0]);
    const float r1 = frelu((pw[3]*rx+pw[4]*ry+pw[5]*rz+pbv[1])*scp[1]+shp[1]);
    const float r2 = frelu((pw[6]*rx+pw[7]*ry+pw[8]*rz+pbv[2])*scp[2]+shp[2]);
    const float4* vv = (const float4*)(vbuf + (size_t)sj*CH);
    float4 res = make_float4(0,0,0,0);
    for (int cc=0; cc<16; ++cc){
        float4 v4 = vv[cc];
        const int c0 = cc*4;
        float d0 = r0*sp2w[(c0+0)*3]+r1*sp2w[(c0+0)*3+1]+r2*sp2w[(c0+0)*3+2]+sp2b[c0+0];
        float d1 = r0*sp2w[(c0+1)*3]+r1*sp2w[(c0+1)*3+1]+r2*sp2w[(c0+1)*3+2]+sp2b[c0+1];
        float d2 = r0*sp2w[(c0+2)*3]+r1*sp2w[(c0+2)*3+1]+r2*sp2w[(c0+2)*3+2]+sp2b[c0+2];
        float d3 = r0*sp2w[(c0+3)*3]+r1*sp2w[(c0+3)*3+1]+r2*sp2w[(c0+3)*3+2]+sp2b[c0+3];
        const int sb = (cc&1)*4;   // channel c -> attn channel c%8
        float m0 = attn[sb+0]*(v4.x+d0);
        float m1 = attn[sb+1]*(v4.y+d1);
        float m2 = attn[sb+2]*(v4.z+d2);
        float m3 = attn[sb+3]*(v4.w+d3);
        #pragma unroll
        for (int msk=8;msk>=1;msk>>=1){
            m0+=__shfl_xor(m0,msk); m1+=__shfl_xor(m1,msk);
            m2+=__shfl_xor(m2,msk); m3+=__shfl_xor(m3,msk);
        }
        if (t == cc) res = make_float4(m0,m1,m2,m3);
    }
    ((float4*)outbuf)[(size_t)i*16 + t] = res;
}

// per-channel sum/sumsq of a [N,64] buffer
__global__ __launch_bounds__(256) void k_stats64(
    const float* __restrict__ data, float* __restrict__ osum, float* __restrict__ osq)
{
    __shared__ float l[128];
    const int tid = threadIdx.x;
    if (tid < 128) l[tid] = 0.f;
    __syncthreads();
    const int g = blockIdx.x*256 + tid;
    const int cc = g & 15;
    float4 s4 = make_float4(0,0,0,0), q4 = make_float4(0,0,0,0);
    for (int r = g >> 4; r < NPTS; r += 4096) {
        float4 v = ((const float4*)data)[(size_t)r*16 + cc];
        s4.x+=v.x; s4.y+=v.y; s4.z+=v.z; s4.w+=v.w;
        q4.x+=v.x*v.x; q4.y+=v.y*v.y; q4.z+=v.z*v.z; q4.w+=v.w*v.w;
    }
    #pragma unroll
    for (int m=32;m>=16;m>>=1){
        s4.x+=__shfl_xor(s4.x,m); s4.y+=__shfl_xor(s4.y,m); s4.z+=__shfl_xor(s4.z,m); s4.w+=__shfl_xor(s4.w,m);
        q4.x+=__shfl_xor(q4.x,m); q4.y+=__shfl_xor(q4.y,m); q4.z+=__shfl_xor(q4.z,m); q4.w+=__shfl_xor(q4.w,m);
    }
    if ((tid & 63) < 16) {
        atomicAdd(&l[cc*4+0], s4.x); atomicAdd(&l[cc*4+1], s4.y);
        atomicAdd(&l[cc*4+2], s4.z); atomicAdd(&l[cc*4+3], s4.w);
        atomicAdd(&l[64+cc*4+0], q4.x); atomicAdd(&l[64+cc*4+1], q4.y);
        atomicAdd(&l[64+cc*4+2], q4.z); atomicAdd(&l[64+cc*4+3], q4.w);
    }
    __syncthreads();
    if (tid < 64) atomicAdd(&osum[tid], l[tid]);
    else if (tid < 128) atomicAdd(&osq[tid-64], l[tid]);
}

// final = relu(bn3(h3) + x_skip)
__global__ __launch_bounds__(256) void k_final(
    const float* __restrict__ h3, const float* __restrict__ x,
    const float* __restrict__ bsum, const float* __restrict__ bsq,
    const float* __restrict__ g, const float* __restrict__ b,
    float* __restrict__ out)
{
    __shared__ float sc[64], sh[64];
    const int tid = threadIdx.x;
    if (tid < 64) {
        float m = bsum[tid]*(1.f/NPTS);
        float v = bsq[tid]*(1.f/NPTS) - m*m;
        float s = g[tid]*rsqrtf(v+EPS);
        sc[tid]=s; sh[tid]=b[tid]-m*s;
    }
    __syncthreads();
    const int gi = blockIdx.x*256 + tid;
    const int c0 = (gi & 15)*4;
    float4 h = ((const float4*)h3)[gi];
    float4 xv = ((const float4*)x)[gi];
    float4 o;
    o.x = fmaxf(h.x*sc[c0+0]+sh[c0+0]+xv.x, 0.f);
    o.y = fmaxf(h.y*sc[c0+1]+sh[c0+1]+xv.y, 0.f);
    o.z = fmaxf(h.z*sc[c0+2]+sh[c0+2]+xv.z, 0.f);
    o.w = fmaxf(h.w*sc[c0+3]+sh[c0+3]+xv.w, 0.f);
    ((float4*)out)[gi] = o;
}

extern "C" void kernel_launch(void* const* d_in, const int* in_sizes, int n_in,
                              void* d_out, int out_size, void* d_ws, size_t ws_size,
                              hipStream_t stream) {
    (void)in_sizes; (void)n_in; (void)out_size; (void)ws_size;
    const float* pos   = (const float*)d_in[0];
    const float* x     = (const float*)d_in[1];
    const float* W1    = (const float*)d_in[2];
    const float* Wk    = (const float*)d_in[3];
    const float* bk    = (const float*)d_in[4];
    const float* Wq    = (const float*)d_in[5];
    const float* bq    = (const float*)d_in[6];
    const float* Wv    = (const float*)d_in[7];
    const float* bv    = (const float*)d_in[8];
    const float* p1w   = (const float*)d_in[9];
    const float* p1b   = (const float*)d_in[10];
    const float* pg    = (const float*)d_in[11];
    const float* pb    = (const float*)d_in[12];
    const float* p2w   = (const float*)d_in[13];
    const float* p2b   = (const float*)d_in[14];
    const float* w1g   = (const float*)d_in[15];
    const float* w1bb  = (const float*)d_in[16];
    const float* w1w   = (const float*)d_in[17];
    const float* w1bias= (const float*)d_in[18];
    const float* w2g   = (const float*)d_in[19];
    const float* w2bb  = (const float*)d_in[20];
    const float* w2w   = (const float*)d_in[21];
    const float* w2bias= (const float*)d_in[22];
    const float* W3    = (const float*)d_in[23];
    const float* bn1g  = (const float*)d_in[24];
    const float* bn1b  = (const float*)d_in[25];
    const float* bn2g  = (const float*)d_in[26];
    const float* bn2b  = (const float*)d_in[27];
    const float* bn3g  = (const float*)d_in[28];
    const float* bn3b  = (const float*)d_in[29];
    const int*   ei    = (const int*)d_in[30];   // [2,E]; row 0 = src
    float* ws  = (float*)d_ws;
    float* out = (float*)d_out;

    hipMemsetAsync(d_ws, 0, 1024*sizeof(float), stream);

    // t1 = x @ W1^T, bn1 stats
    k_gemm64<<<512, 64, 0, stream>>>(x, W1, ws+OFF_T1,
        nullptr, nullptr, nullptr, nullptr, 0, ws+OFF_BN1S, ws+OFF_BN1Q);
    // p_bn stats (independent)
    k_pstats<<<256, 256, 0, stream>>>(pos, ei, p1w, p1b, ws+OFF_PS, ws+OFF_PQ);
    // k,q,v
    k_kqv<<<512, 64, 0, stream>>>(ws+OFF_T1, Wk, bk, Wq, bq, Wv, bv,
        ws+OFF_BN1S, ws+OFF_BN1Q, bn1g, bn1b, ws+OFF_K, ws+OFF_Q, ws+OFF_V);
    // w_bn1 stats
    k_edge1<<<512, 256, 0, stream>>>(pos, ei, ws+OFF_K, ws+OFF_Q,
        p1w, p1b, pg, pb, p2w, p2b, ws+OFF_PS, ws+OFF_PQ, ws+OFF_W1S, ws+OFF_W1Q);
    // a2 + w_bn2 stats
    k_edge2<<<512, 256, 0, stream>>>(pos, ei, ws+OFF_K, ws+OFF_Q,
        p1w, p1b, pg, pb, p2w, p2b, ws+OFF_PS, ws+OFF_PQ,
        ws+OFF_W1S, ws+OFF_W1Q, w1g, w1bb, w1w, w1bias,
        ws+OFF_A2, ws+OFF_W2S, ws+OFF_W2Q);
    // softmax + aggregate
    k_attn<<<2048, 256, 0, stream>>>(pos, ei, ws+OFF_V, ws+OFF_A2,
        p1w, p1b, pg, pb, p2w, p2b, ws+OFF_PS, ws+OFF_PQ,
        ws+OFF_W2S, ws+OFF_W2Q, w2g, w2bb, w2w, w2bias, ws+OFF_OUT);
    // bn2 stats
    k_stats64<<<256, 256, 0, stream>>>(ws+OFF_OUT, ws+OFF_BN2S, ws+OFF_BN2Q);
    // h3 = relu(bn2(out)) @ W3^T, bn3 stats
    k_gemm64<<<512, 64, 0, stream>>>(ws+OFF_OUT, W3, ws+OFF_H3,
        ws+OFF_BN2S, ws+OFF_BN2Q, bn2g, bn2b, 1, ws+OFF_BN3S, ws+OFF_BN3Q);
    // final
    k_final<<<2048, 256, 0, stream>>>(ws+OFF_H3, x, ws+OFF_BN3S, ws+OFF_BN3Q, bn3g, bn3b, out);
}

// Round 2
// 454.403 us; speedup vs baseline: 2.1744x; 2.1744x over previous
//
#include <hip/hip_runtime.h>

#define NPTS 32768
#define CH 64
#define KNN 16
#define NE (NPTS*KNN)
#define EPS 1e-5f
#define NREP 16

// stats groups: NREP replicas x 128 floats; sums at [c], sumsq at [64+c]
#define G_P   0
#define G_BN1 2048
#define G_W1  4096
#define G_W2  6144
#define G_BN2 8192
#define G_BN3 10240
#define STATS_FLOATS 12288

#define OFF_T1  16384
#define SZ_NC   (NPTS*CH)
#define OFF_K   (OFF_T1 + SZ_NC)
#define OFF_Q   (OFF_K + SZ_NC)
#define OFF_V   (OFF_Q + SZ_NC)
#define OFF_A2  (OFF_V + SZ_NC)
#define OFF_OUT (OFF_A2 + NE*8)
#define OFF_U   (OFF_OUT + SZ_NC)   /* NE*4 floats; shared with H3 (dead by then) */
#define OFF_H3  OFF_U

__device__ __forceinline__ float frelu(float x){ return fmaxf(x, 0.f); }

// reduce a stats group (NREP x 128) and produce scale/shift in LDS arrays (nch<=64)
#define LOAD_SCSH(grp, invc, gptr, bptr, scA, shA, nch) do {                        \
    if (tid < 128) { float t_ = 0.f;                                                \
        _Pragma("unroll") for (int r_ = 0; r_ < NREP; ++r_) t_ += (grp)[r_*128+tid];\
        s_tmp[tid] = t_; }                                                          \
    __syncthreads();                                                                \
    if (tid < (nch)) { float m_ = s_tmp[tid]*(invc);                                \
        float v_ = s_tmp[64+tid]*(invc) - m_*m_;                                    \
        float s_ = (gptr)[tid]*rsqrtf(v_+EPS);                                      \
        (scA)[tid] = s_; (shA)[tid] = (bptr)[tid] - m_*s_; }                        \
    __syncthreads();                                                                \
} while(0)

// ---------- u = rel @ p1_w^T + p1_b per edge (stored), plus p-bn stats ----------
__global__ __launch_bounds__(256) void k_pstats_u(
    const float* __restrict__ pos, const int* __restrict__ esrc,
    const float* __restrict__ p1w, const float* __restrict__ p1b,
    float4* __restrict__ u4, float* __restrict__ gstat)
{
    __shared__ float red[4][6];
    const int tid = threadIdx.x;
    float w[9], b3[3];
    #pragma unroll
    for (int i=0;i<9;++i) w[i]=p1w[i];
    b3[0]=p1b[0]; b3[1]=p1b[1]; b3[2]=p1b[2];
    float s0=0,s1=0,s2=0,q0=0,q1=0,q2=0;
    for (int e = blockIdx.x*256 + tid; e < NE; e += 128*256) {
        int sj = esrc[e]; int d = e >> 4;
        float ax = pos[3*sj]-pos[3*d], ay = pos[3*sj+1]-pos[3*d+1], az = pos[3*sj+2]-pos[3*d+2];
        float u0 = w[0]*ax+w[1]*ay+w[2]*az+b3[0];
        float u1 = w[3]*ax+w[4]*ay+w[5]*az+b3[1];
        float u2 = w[6]*ax+w[7]*ay+w[8]*az+b3[2];
        u4[e] = make_float4(u0,u1,u2,0.f);
        s0+=u0; s1+=u1; s2+=u2; q0+=u0*u0; q1+=u1*u1; q2+=u2*u2;
    }
    #pragma unroll
    for (int m=32;m>=1;m>>=1){
        s0+=__shfl_xor(s0,m); s1+=__shfl_xor(s1,m); s2+=__shfl_xor(s2,m);
        q0+=__shfl_xor(q0,m); q1+=__shfl_xor(q1,m); q2+=__shfl_xor(q2,m);
    }
    const int wv = tid>>6;
    if ((tid&63)==0){ red[wv][0]=s0; red[wv][1]=s1; red[wv][2]=s2;
                      red[wv][3]=q0; red[wv][4]=q1; red[wv][5]=q2; }
    __syncthreads();
    float* g = gstat + (blockIdx.x & (NREP-1))*128;
    if (tid < 3)      atomicAdd(&g[tid],        red[0][tid]+red[1][tid]+red[2][tid]+red[3][tid]);
    else if (tid < 6) atomicAdd(&g[64+(tid-3)], red[0][tid]+red[1][tid]+red[2][tid]+red[3][tid]);
}

// ---------- per-channel sum/sumsq of a [NPTS,64] buffer (lane = channel) ----------
__global__ __launch_bounds__(256) void k_stats_nc(
    const float* __restrict__ data, float* __restrict__ gstat)
{
    __shared__ float red[4][128];
    const int tid = threadIdx.x;
    const int c = tid & 63, wv = tid >> 6;
    const int gw = blockIdx.x*4 + wv;           // 1024 waves
    float s=0.f, q=0.f;
    #pragma unroll 4
    for (int r = gw; r < NPTS; r += 1024) {
        float v = data[(size_t)r*CH + c];
        s += v; q += v*v;
    }
    red[wv][c] = s; red[wv][64+c] = q;
    __syncthreads();
    if (tid < 128) {
        float t = red[0][tid]+red[1][tid]+red[2][tid]+red[3][tid];
        atomicAdd(&gstat[(blockIdx.x & (NREP-1))*128 + tid], t);
    }
}

// ---------- [N,64]@W^T, optional input bn+relu (thread = row) ----------
__global__ __launch_bounds__(256) void k_gemm64(
    const float* __restrict__ in, const float* __restrict__ W,
    float* __restrict__ out,
    const float* __restrict__ bnrep, const float* __restrict__ bng,
    const float* __restrict__ bnb, int applyBn)
{
    __shared__ float Wl[CH*CH];
    __shared__ float s_tmp[128];
    __shared__ float sc[64], sh[64];
    const int tid = threadIdx.x;
    {
        const float4* W4 = (const float4*)W;
        float4* Wl4 = (float4*)Wl;
        #pragma unroll
        for (int i=0;i<4;++i) Wl4[i*256+tid] = W4[i*256+tid];
    }
    if (applyBn) { LOAD_SCSH(bnrep, 1.f/NPTS, bng, bnb, sc, sh, 64); }
    __syncthreads();

    const int row = blockIdx.x*256 + tid;
    float xr[CH];
    {
        const float4* iv = (const float4*)(in + (size_t)row*CH);
        #pragma unroll
        for (int i=0;i<16;++i){ float4 t=iv[i];
            xr[4*i]=t.x; xr[4*i+1]=t.y; xr[4*i+2]=t.z; xr[4*i+3]=t.w; }
    }
    if (applyBn){
        #pragma unroll
        for (int i=0;i<CH;++i) xr[i] = frelu(xr[i]*sc[i]+sh[i]);
    }
    float4* ov = (float4*)(out + (size_t)row*CH);
    for (int cc=0; cc<16; ++cc){
        float4 acc = make_float4(0,0,0,0);
        const float* w0=&Wl[(cc*4+0)*CH];
        const float* w1=&Wl[(cc*4+1)*CH];
        const float* w2=&Wl[(cc*4+2)*CH];
        const float* w3=&Wl[(cc*4+3)*CH];
        #pragma unroll
        for (int i=0;i<CH;++i){ float xv=xr[i];
            acc.x+=xv*w0[i]; acc.y+=xv*w1[i]; acc.z+=xv*w2[i]; acc.w+=xv*w3[i]; }
        ov[cc]=acc;
    }
}

// ---------- k/q/v: m = blockIdx/128 selects matrix ----------
__global__ __launch_bounds__(256) void k_kqv(
    const float* __restrict__ t1,
    const float* __restrict__ Wk, const float* __restrict__ bk,
    const float* __restrict__ Wq, const float* __restrict__ bq,
    const float* __restrict__ Wv, const float* __restrict__ bv,
    const float* __restrict__ bnrep, const float* __restrict__ bng,
    const float* __restrict__ bnb,
    float* __restrict__ kout, float* __restrict__ qout, float* __restrict__ vout)
{
    __shared__ float Wl[CH*CH];
    __shared__ float bias[64];
    __shared__ float s_tmp[128];
    __shared__ float sc[64], sh[64];
    const int tid = threadIdx.x;
    const int m = blockIdx.x >> 7;
    const int rb = blockIdx.x & 127;
    const float* W  = (m==0) ? Wk : (m==1 ? Wq : Wv);
    const float* bs = (m==0) ? bk : (m==1 ? bq : bv);
    float* o        = (m==0) ? kout : (m==1 ? qout : vout);
    {
        const float4* W4 = (const float4*)W;
        float4* Wl4 = (float4*)Wl;
        #pragma unroll
        for (int i=0;i<4;++i) Wl4[i*256+tid] = W4[i*256+tid];
    }
    if (tid < 64) bias[tid] = bs[tid];
    LOAD_SCSH(bnrep, 1.f/NPTS, bng, bnb, sc, sh, 64);

    const int row = rb*256 + tid;
    float h[CH];
    {
        const float4* iv = (const float4*)(t1 + (size_t)row*CH);
        #pragma unroll
        for (int i=0;i<16;++i){ float4 t=iv[i];
            h[4*i]=t.x; h[4*i+1]=t.y; h[4*i+2]=t.z; h[4*i+3]=t.w; }
    }
    #pragma unroll
    for (int i=0;i<CH;++i) h[i] = frelu(h[i]*sc[i]+sh[i]);

    float4* ov = (float4*)(o + (size_t)row*CH);
    for (int cc=0; cc<16; ++cc){
        float4 acc = make_float4(bias[cc*4], bias[cc*4+1], bias[cc*4+2], bias[cc*4+3]);
        const float* w0=&Wl[(cc*4+0)*CH];
        const float* w1=&Wl[(cc*4+1)*CH];
        const float* w2=&Wl[(cc*4+2)*CH];
        const float* w3=&Wl[(cc*4+3)*CH];
        #pragma unroll
        for (int i=0;i<CH;++i){ float xv=h[i];
            acc.x+=xv*w0[i]; acc.y+=xv*w1[i]; acc.z+=xv*w2[i]; acc.w+=xv*w3[i]; }
        ov[cc]=acc;
    }
}

// ---------- w_bn1 stats over apre = k[src]-q[dst]+delta (lane = channel) ----------
__global__ __launch_bounds__(256) void k_edge1(
    const int* __restrict__ esrc, const float4* __restrict__ u4,
    const float* __restrict__ kbuf, const float* __restrict__ qbuf,
    const float* __restrict__ prep, const float* __restrict__ pg,
    const float* __restrict__ pb,
    const float* __restrict__ p2w, const float* __restrict__ p2b,
    float* __restrict__ gstat)
{
    __shared__ float red[4][128];
    __shared__ float s_tmp[128];
    __shared__ float scL[64], shL[64];
    const int tid = threadIdx.x;
    const int c = tid & 63, wv = tid >> 6;
    LOAD_SCSH(prep, 1.f/NE, pg, pb, scL, shL, 3);
    const float scp0=scL[0], scp1=scL[1], scp2=scL[2];
    const float shp0=shL[0], shp1=shL[1], shp2=shL[2];
    const float w0 = p2w[c*3+0], w1 = p2w[c*3+1], w2 = p2w[c*3+2], bc = p2b[c];

    const int gw = blockIdx.x*4 + wv;      // 1024 waves
    const int chunk = NE/1024;             // 512 edges/wave, contiguous for q-reuse
    const int e0 = gw*chunk;
    float s=0.f, q=0.f;
    #pragma unroll 2
    for (int e = e0; e < e0+chunk; ++e) {
        int sj = esrc[e]; int d = e >> 4;
        float4 uu = u4[e];
        float r0 = frelu(uu.x*scp0+shp0);
        float r1 = frelu(uu.y*scp1+shp1);
        float r2 = frelu(uu.z*scp2+shp2);
        float a = kbuf[(size_t)sj*CH+c] - qbuf[(size_t)d*CH+c]
                + (r0*w0 + r1*w1 + r2*w2 + bc);
        s += a; q += a*a;
    }
    red[wv][c] = s; red[wv][64+c] = q;
    __syncthreads();
    if (tid < 128) {
        float t = red[0][tid]+red[1][tid]+red[2][tid]+red[3][tid];
        atomicAdd(&gstat[(blockIdx.x & (NREP-1))*128 + tid], t);
    }
}

// ---------- a2 = relu(bn_w1(apre))@w1^T+b1 ; store ; w_bn2 stats (thread = edge) ----------
__global__ __launch_bounds__(256) void k_edge2(
    const int* __restrict__ esrc, const float4* __restrict__ u4,
    const float* __restrict__ kbuf, const float* __restrict__ qbuf,
    const float* __restrict__ prep, const float* __restrict__ pg,
    const float* __restrict__ pb,
    const float* __restrict__ p2w, const float* __restrict__ p2b,
    const float* __restrict__ w1rep, const float* __restrict__ w1g,
    const float* __restrict__ w1bn_b,
    const float* __restrict__ w1w, const float* __restrict__ w1bias,
    float* __restrict__ a2out, float* __restrict__ gstat)
{
    __shared__ float sp2w[192], sp2b[64], sw1[512], sw1b[8];
    __shared__ float s_tmp[128];
    __shared__ float scp[64], shp[64];
    __shared__ float sc1[64], sh1[64];
    __shared__ float red[4][16];
    const int tid = threadIdx.x;
    if (tid < 192) sp2w[tid] = p2w[tid];
    if (tid < 64)  sp2b[tid] = p2b[tid];
    sw1[tid] = w1w[tid]; sw1[256+tid] = w1w[256+tid];
    if (tid < 8) sw1b[tid] = w1bias[tid];
    LOAD_SCSH(prep, 1.f/NE, pg, pb, scp, shp, 3);
    LOAD_SCSH(w1rep, 1.f/NE, w1g, w1bn_b, sc1, sh1, 64);
    const float scp0=scp[0], scp1=scp[1], scp2=scp[2];
    const float shp0=shp[0], shp1=shp[1], shp2=shp[2];

    float s8[8] = {0,0,0,0,0,0,0,0}, q8[8] = {0,0,0,0,0,0,0,0};
    for (int e = blockIdx.x*256 + tid; e < NE; e += 256*256) {
        const int sj = esrc[e]; const int d = e >> 4;
        float4 uu = u4[e];
        const float r0 = frelu(uu.x*scp0+shp0);
        const float r1 = frelu(uu.y*scp1+shp1);
        const float r2 = frelu(uu.z*scp2+shp2);
        const float4* kv = (const float4*)(kbuf + (size_t)sj*CH);
        const float4* qv = (const float4*)(qbuf + (size_t)d*CH);
        float a2a[8];
        #pragma unroll
        for (int j=0;j<8;++j) a2a[j] = sw1b[j];
        for (int cc=0; cc<16; ++cc) {
            float4 k4 = kv[cc], q4 = qv[cc];
            const int c0 = cc*4;
            float b0 = frelu((k4.x - q4.x + r0*sp2w[(c0+0)*3]+r1*sp2w[(c0+0)*3+1]+r2*sp2w[(c0+0)*3+2]+sp2b[c0+0])*sc1[c0+0]+sh1[c0+0]);
            float b1 = frelu((k4.y - q4.y + r0*sp2w[(c0+1)*3]+r1*sp2w[(c0+1)*3+1]+r2*sp2w[(c0+1)*3+2]+sp2b[c0+1])*sc1[c0+1]+sh1[c0+1]);
            float b2 = frelu((k4.z - q4.z + r0*sp2w[(c0+2)*3]+r1*sp2w[(c0+2)*3+1]+r2*sp2w[(c0+2)*3+2]+sp2b[c0+2])*sc1[c0+2]+sh1[c0+2]);
            float b3 = frelu((k4.w - q4.w + r0*sp2w[(c0+3)*3]+r1*sp2w[(c0+3)*3+1]+r2*sp2w[(c0+3)*3+2]+sp2b[c0+3])*sc1[c0+3]+sh1[c0+3]);
            #pragma unroll
            for (int j=0;j<8;++j)
                a2a[j] += b0*sw1[j*64+c0] + b1*sw1[j*64+c0+1] + b2*sw1[j*64+c0+2] + b3*sw1[j*64+c0+3];
        }
        float4* a2v = (float4*)(a2out + (size_t)e*8);
        a2v[0] = make_float4(a2a[0],a2a[1],a2a[2],a2a[3]);
        a2v[1] = make_float4(a2a[4],a2a[5],a2a[6],a2a[7]);
        #pragma unroll
        for (int j=0;j<8;++j){ s8[j]+=a2a[j]; q8[j]+=a2a[j]*a2a[j]; }
    }
    #pragma unroll
    for (int m=32;m>=1;m>>=1){
        #pragma unroll
        for (int j=0;j<8;++j){ s8[j]+=__shfl_xor(s8[j],m); q8[j]+=__shfl_xor(q8[j],m); }
    }
    const int wv = tid>>6;
    if ((tid&63)==0){
        #pragma unroll
        for (int j=0;j<8;++j){ red[wv][j]=s8[j]; red[wv][8+j]=q8[j]; }
    }
    __syncthreads();
    if (tid < 16) {
        float t = red[0][tid]+red[1][tid]+red[2][tid]+red[3][tid];
        int dstc = (tid<8) ? tid : (64 + tid - 8);
        atomicAdd(&gstat[(blockIdx.x & (NREP-1))*128 + dstc], t);
    }
}

// ---------- bn_w2 + w2 matmul + 16-way softmax + weighted aggregation ----------
__global__ __launch_bounds__(256) void k_attn(
    const int* __restrict__ esrc, const float4* __restrict__ u4,
    const float* __restrict__ vbuf, const float* __restrict__ a2buf,
    const float* __restrict__ prep, const float* __restrict__ pg,
    const float* __restrict__ pb,
    const float* __restrict__ p2w, const float* __restrict__ p2b,
    const float* __restrict__ w2rep, const float* __restrict__ w2g,
    const float* __restrict__ w2bn_b,
    const float* __restrict__ w2w, const float* __restrict__ w2bias,
    float* __restrict__ outbuf)
{
    __shared__ float sp2w[192], sp2b[64], sw2[64], sw2b[8];
    __shared__ float s_tmp[128];
    __shared__ float scp[64], shp[64];
    __shared__ float sc2[64], sh2[64];
    const int tid = threadIdx.x;
    if (tid < 192) sp2w[tid] = p2w[tid];
    if (tid < 64) { sp2b[tid] = p2b[tid]; sw2[tid] = w2w[tid]; }
    if (tid < 8)  sw2b[tid] = w2bias[tid];
    LOAD_SCSH(prep, 1.f/NE, pg, pb, scp, shp, 3);
    LOAD_SCSH(w2rep, 1.f/NE, w2g, w2bn_b, sc2, sh2, 8);
    const float scp0=scp[0], scp1=scp[1], scp2=scp[2];
    const float shp0=shp[0], shp1=shp[1], shp2=shp[2];

    const int t = tid & 15;
    const int i = blockIdx.x*16 + (tid>>4);
    const int e = i*KNN + t;
    const int sj = esrc[e];

    const float4* a2v = (const float4*)a2buf;
    float4 aA = a2v[(size_t)e*2], aB = a2v[(size_t)e*2+1];
    float bb[8];
    bb[0]=frelu(aA.x*sc2[0]+sh2[0]); bb[1]=frelu(aA.y*sc2[1]+sh2[1]);
    bb[2]=frelu(aA.z*sc2[2]+sh2[2]); bb[3]=frelu(aA.w*sc2[3]+sh2[3]);
    bb[4]=frelu(aB.x*sc2[4]+sh2[4]); bb[5]=frelu(aB.y*sc2[5]+sh2[5]);
    bb[6]=frelu(aB.z*sc2[6]+sh2[6]); bb[7]=frelu(aB.w*sc2[7]+sh2[7]);
    float attn[8];
    #pragma unroll
    for (int s=0;s<8;++s){
        float a3 = sw2b[s];
        #pragma unroll
        for (int u=0;u<8;++u) a3 += bb[u]*sw2[s*8+u];
        attn[s]=a3;
    }
    #pragma unroll
    for (int s=0;s<8;++s){
        float m = attn[s];
        #pragma unroll
        for (int msk=8;msk>=1;msk>>=1) m = fmaxf(m, __shfl_xor(m,msk));
        float p = __expf(attn[s]-m);
        float ssm = p;
        #pragma unroll
        for (int msk=8;msk>=1;msk>>=1) ssm += __shfl_xor(ssm,msk);
        attn[s] = p/ssm;
    }
    float4 uu = u4[e];
    const float r0 = frelu(uu.x*scp0+shp0);
    const float r1 = frelu(uu.y*scp1+shp1);
    const float r2 = frelu(uu.z*scp2+shp2);
    const float4* vv = (const float4*)(vbuf + (size_t)sj*CH);
    float4 res = make_float4(0,0,0,0);
    for (int cc=0; cc<16; ++cc){
        float4 v4 = vv[cc];
        const int c0 = cc*4;
        float d0 = r0*sp2w[(c0+0)*3]+r1*sp2w[(c0+0)*3+1]+r2*sp2w[(c0+0)*3+2]+sp2b[c0+0];
        float d1 = r0*sp2w[(c0+1)*3]+r1*sp2w[(c0+1)*3+1]+r2*sp2w[(c0+1)*3+2]+sp2b[c0+1];
        float d2 = r0*sp2w[(c0+2)*3]+r1*sp2w[(c0+2)*3+1]+r2*sp2w[(c0+2)*3+2]+sp2b[c0+2];
        float d3 = r0*sp2w[(c0+3)*3]+r1*sp2w[(c0+3)*3+1]+r2*sp2w[(c0+3)*3+2]+sp2b[c0+3];
        const int sb = (cc&1)*4;
        float m0 = attn[sb+0]*(v4.x+d0);
        float m1 = attn[sb+1]*(v4.y+d1);
        float m2 = attn[sb+2]*(v4.z+d2);
        float m3 = attn[sb+3]*(v4.w+d3);
        #pragma unroll
        for (int msk=8;msk>=1;msk>>=1){
            m0+=__shfl_xor(m0,msk); m1+=__shfl_xor(m1,msk);
            m2+=__shfl_xor(m2,msk); m3+=__shfl_xor(m3,msk);
        }
        if (t == cc) res = make_float4(m0,m1,m2,m3);
    }
    ((float4*)outbuf)[(size_t)i*16 + t] = res;
}

// ---------- final = relu(bn3(h3) + x_skip) ----------
__global__ __launch_bounds__(256) void k_final(
    const float* __restrict__ h3, const float* __restrict__ x,
    const float* __restrict__ bnrep, const float* __restrict__ g,
    const float* __restrict__ b, float* __restrict__ out)
{
    __shared__ float s_tmp[128];
    __shared__ float sc[64], sh[64];
    const int tid = threadIdx.x;
    LOAD_SCSH(bnrep, 1.f/NPTS, g, b, sc, sh, 64);
    const int gi = blockIdx.x*256 + tid;
    const int c0 = (gi & 15)*4;
    float4 h = ((const float4*)h3)[gi];
    float4 xv = ((const float4*)x)[gi];
    float4 o;
    o.x = fmaxf(h.x*sc[c0+0]+sh[c0+0]+xv.x, 0.f);
    o.y = fmaxf(h.y*sc[c0+1]+sh[c0+1]+xv.y, 0.f);
    o.z = fmaxf(h.z*sc[c0+2]+sh[c0+2]+xv.z, 0.f);
    o.w = fmaxf(h.w*sc[c0+3]+sh[c0+3]+xv.w, 0.f);
    ((float4*)out)[gi] = o;
}

extern "C" void kernel_launch(void* const* d_in, const int* in_sizes, int n_in,
                              void* d_out, int out_size, void* d_ws, size_t ws_size,
                              hipStream_t stream) {
    (void)in_sizes; (void)n_in; (void)out_size; (void)ws_size;
    const float* pos   = (const float*)d_in[0];
    const float* x     = (const float*)d_in[1];
    const float* W1    = (const float*)d_in[2];
    const float* Wk    = (const float*)d_in[3];
    const float* bk    = (const float*)d_in[4];
    const float* Wq    = (const float*)d_in[5];
    const float* bq    = (const float*)d_in[6];
    const float* Wv    = (const float*)d_in[7];
    const float* bv    = (const float*)d_in[8];
    const float* p1w   = (const float*)d_in[9];
    const float* p1b   = (const float*)d_in[10];
    const float* pg    = (const float*)d_in[11];
    const float* pb    = (const float*)d_in[12];
    const float* p2w   = (const float*)d_in[13];
    const float* p2b   = (const float*)d_in[14];
    const float* w1g   = (const float*)d_in[15];
    const float* w1bb  = (const float*)d_in[16];
    const float* w1w   = (const float*)d_in[17];
    const float* w1bias= (const float*)d_in[18];
    const float* w2g   = (const float*)d_in[19];
    const float* w2bb  = (const float*)d_in[20];
    const float* w2w   = (const float*)d_in[21];
    const float* w2bias= (const float*)d_in[22];
    const float* W3    = (const float*)d_in[23];
    const float* bn1g  = (const float*)d_in[24];
    const float* bn1b  = (const float*)d_in[25];
    const float* bn2g  = (const float*)d_in[26];
    const float* bn2b  = (const float*)d_in[27];
    const float* bn3g  = (const float*)d_in[28];
    const float* bn3b  = (const float*)d_in[29];
    const int*   ei    = (const int*)d_in[30];
    float* ws  = (float*)d_ws;
    float* out = (float*)d_out;

    hipMemsetAsync(ws, 0, STATS_FLOATS*sizeof(float), stream);

    // u precompute + p-bn stats (independent of GEMM chain)
    k_pstats_u<<<128, 256, 0, stream>>>(pos, ei, p1w, p1b,
        (float4*)(ws+OFF_U), ws+G_P);
    // t1 = x @ W1^T
    k_gemm64<<<128, 256, 0, stream>>>(x, W1, ws+OFF_T1, nullptr, nullptr, nullptr, 0);
    // bn1 stats
    k_stats_nc<<<256, 256, 0, stream>>>(ws+OFF_T1, ws+G_BN1);
    // k,q,v
    k_kqv<<<384, 256, 0, stream>>>(ws+OFF_T1, Wk, bk, Wq, bq, Wv, bv,
        ws+G_BN1, bn1g, bn1b, ws+OFF_K, ws+OFF_Q, ws+OFF_V);
    // w_bn1 stats
    k_edge1<<<256, 256, 0, stream>>>(ei, (const float4*)(ws+OFF_U),
        ws+OFF_K, ws+OFF_Q, ws+G_P, pg, pb, p2w, p2b, ws+G_W1);
    // a2 + w_bn2 stats
    k_edge2<<<256, 256, 0, stream>>>(ei, (const float4*)(ws+OFF_U),
        ws+OFF_K, ws+OFF_Q, ws+G_P, pg, pb, p2w, p2b,
        ws+G_W1, w1g, w1bb, w1w, w1bias, ws+OFF_A2, ws+G_W2);
    // softmax + aggregate
    k_attn<<<2048, 256, 0, stream>>>(ei, (const float4*)(ws+OFF_U),
        ws+OFF_V, ws+OFF_A2, ws+G_P, pg, pb, p2w, p2b,
        ws+G_W2, w2g, w2bb, w2w, w2bias, ws+OFF_OUT);
    // bn2 stats
    k_stats_nc<<<256, 256, 0, stream>>>(ws+OFF_OUT, ws+G_BN2);
    // h3 = relu(bn2(out)) @ W3^T
    k_gemm64<<<128, 256, 0, stream>>>(ws+OFF_OUT, W3, ws+OFF_H3,
        ws+G_BN2, bn2g, bn2b, 1);
    // bn3 stats
    k_stats_nc<<<256, 256, 0, stream>>>(ws+OFF_H3, ws+G_BN3);
    // final
    k_final<<<2048, 256, 0, stream>>>(ws+OFF_H3, x, ws+G_BN3, bn3g, bn3b, out);
}

// Round 3
// 367.043 us; speedup vs baseline: 2.6920x; 1.2380x over previous
//
#include <hip/hip_runtime.h>

#define NPTS 32768
#define CH 64
#define KNN 16
#define NE (NPTS*KNN)
#define EPS 1e-5f
#define NREP 16

// stats groups: NREP replicas x 128 floats; sums at [c], sumsq at [64+c]
#define G_P   0
#define G_BN1 2048
#define G_W1  4096
#define G_W2  6144
#define G_BN2 8192
#define G_BN3 10240
#define STATS_FLOATS 12288

#define OFF_T1  16384
#define SZ_NC   (NPTS*CH)
#define OFF_K   (OFF_T1 + SZ_NC)
#define OFF_Q   (OFF_K + SZ_NC)
#define OFF_V   (OFF_Q + SZ_NC)
#define OFF_A2  (OFF_V + SZ_NC)
#define OFF_OUT (OFF_A2 + NE*8)
#define OFF_U   (OFF_OUT + SZ_NC)   /* NE*4 floats; shared with H3 (dead by then) */
#define OFF_H3  OFF_U

__device__ __forceinline__ float frelu(float x){ return fmaxf(x, 0.f); }

// reduce a stats group (NREP x 128) and produce scale/shift in LDS arrays (nch<=64)
#define LOAD_SCSH(grp, invc, gptr, bptr, scA, shA, nch) do {                        \
    if (tid < 128) { float t_ = 0.f;                                                \
        _Pragma("unroll") for (int r_ = 0; r_ < NREP; ++r_) t_ += (grp)[r_*128+tid];\
        s_tmp[tid] = t_; }                                                          \
    __syncthreads();                                                                \
    if (tid < (nch)) { float m_ = s_tmp[tid]*(invc);                                \
        float v_ = s_tmp[64+tid]*(invc) - m_*m_;                                    \
        float s_ = (gptr)[tid]*rsqrtf(v_+EPS);                                      \
        (scA)[tid] = s_; (shA)[tid] = (bptr)[tid] - m_*s_; }                        \
    __syncthreads();                                                                \
} while(0)

// ---------- u = rel @ p1_w^T + p1_b per edge (stored), plus p-bn stats ----------
__global__ __launch_bounds__(256) void k_pstats_u(
    const float* __restrict__ pos, const int* __restrict__ esrc,
    const float* __restrict__ p1w, const float* __restrict__ p1b,
    float4* __restrict__ u4, float* __restrict__ gstat)
{
    __shared__ float red[4][6];
    const int tid = threadIdx.x;
    float w[9], b3[3];
    #pragma unroll
    for (int i=0;i<9;++i) w[i]=p1w[i];
    b3[0]=p1b[0]; b3[1]=p1b[1]; b3[2]=p1b[2];
    float s0=0,s1=0,s2=0,q0=0,q1=0,q2=0;
    for (int e = blockIdx.x*256 + tid; e < NE; e += 1024*256) {
        int sj = esrc[e]; int d = e >> 4;
        float ax = pos[3*sj]-pos[3*d], ay = pos[3*sj+1]-pos[3*d+1], az = pos[3*sj+2]-pos[3*d+2];
        float u0 = w[0]*ax+w[1]*ay+w[2]*az+b3[0];
        float u1 = w[3]*ax+w[4]*ay+w[5]*az+b3[1];
        float u2 = w[6]*ax+w[7]*ay+w[8]*az+b3[2];
        u4[e] = make_float4(u0,u1,u2,0.f);
        s0+=u0; s1+=u1; s2+=u2; q0+=u0*u0; q1+=u1*u1; q2+=u2*u2;
    }
    #pragma unroll
    for (int m=32;m>=1;m>>=1){
        s0+=__shfl_xor(s0,m); s1+=__shfl_xor(s1,m); s2+=__shfl_xor(s2,m);
        q0+=__shfl_xor(q0,m); q1+=__shfl_xor(q1,m); q2+=__shfl_xor(q2,m);
    }
    const int wv = tid>>6;
    if ((tid&63)==0){ red[wv][0]=s0; red[wv][1]=s1; red[wv][2]=s2;
                      red[wv][3]=q0; red[wv][4]=q1; red[wv][5]=q2; }
    __syncthreads();
    float* g = gstat + (blockIdx.x & (NREP-1))*128;
    if (tid < 3)      atomicAdd(&g[tid],        red[0][tid]+red[1][tid]+red[2][tid]+red[3][tid]);
    else if (tid < 6) atomicAdd(&g[64+(tid-3)], red[0][tid]+red[1][tid]+red[2][tid]+red[3][tid]);
}

// ---------- [N,64]@W^T, optional input bn+relu (thread = row), fused output stats ----------
__global__ __launch_bounds__(256) void k_gemm64(
    const float* __restrict__ in, const float* __restrict__ W,
    float* __restrict__ out,
    const float* __restrict__ bnrep, const float* __restrict__ bng,
    const float* __restrict__ bnb, int applyBn,
    float* __restrict__ gstat)
{
    __shared__ float Wl[CH*CH];
    __shared__ float s_tmp[128];
    __shared__ float sc[64], sh[64];
    __shared__ float red[4][128];
    const int tid = threadIdx.x;
    const int wv = tid >> 6;
    {
        const float4* W4 = (const float4*)W;
        float4* Wl4 = (float4*)Wl;
        #pragma unroll
        for (int i=0;i<4;++i) Wl4[i*256+tid] = W4[i*256+tid];
    }
    if (applyBn) { LOAD_SCSH(bnrep, 1.f/NPTS, bng, bnb, sc, sh, 64); }
    __syncthreads();

    const int row = blockIdx.x*256 + tid;
    float xr[CH];
    {
        const float4* iv = (const float4*)(in + (size_t)row*CH);
        #pragma unroll
        for (int i=0;i<16;++i){ float4 t=iv[i];
            xr[4*i]=t.x; xr[4*i+1]=t.y; xr[4*i+2]=t.z; xr[4*i+3]=t.w; }
    }
    if (applyBn){
        #pragma unroll
        for (int i=0;i<CH;++i) xr[i] = frelu(xr[i]*sc[i]+sh[i]);
    }
    float4* ov = (float4*)(out + (size_t)row*CH);
    for (int cc=0; cc<16; ++cc){
        float4 acc = make_float4(0,0,0,0);
        const float* w0=&Wl[(cc*4+0)*CH];
        const float* w1=&Wl[(cc*4+1)*CH];
        const float* w2=&Wl[(cc*4+2)*CH];
        const float* w3=&Wl[(cc*4+3)*CH];
        #pragma unroll
        for (int i=0;i<CH;++i){ float xv=xr[i];
            acc.x+=xv*w0[i]; acc.y+=xv*w1[i]; acc.z+=xv*w2[i]; acc.w+=xv*w3[i]; }
        ov[cc]=acc;
        float4 sq = make_float4(acc.x*acc.x, acc.y*acc.y, acc.z*acc.z, acc.w*acc.w);
        #pragma unroll
        for (int m=32;m>=1;m>>=1){
            acc.x+=__shfl_xor(acc.x,m); acc.y+=__shfl_xor(acc.y,m);
            acc.z+=__shfl_xor(acc.z,m); acc.w+=__shfl_xor(acc.w,m);
            sq.x+=__shfl_xor(sq.x,m);  sq.y+=__shfl_xor(sq.y,m);
            sq.z+=__shfl_xor(sq.z,m);  sq.w+=__shfl_xor(sq.w,m);
        }
        if ((tid&63)==0){
            const int c0 = cc*4;
            red[wv][c0]=acc.x; red[wv][c0+1]=acc.y; red[wv][c0+2]=acc.z; red[wv][c0+3]=acc.w;
            red[wv][64+c0]=sq.x; red[wv][64+c0+1]=sq.y; red[wv][64+c0+2]=sq.z; red[wv][64+c0+3]=sq.w;
        }
    }
    __syncthreads();
    if (tid < 128) {
        float t = red[0][tid]+red[1][tid]+red[2][tid]+red[3][tid];
        atomicAdd(&gstat[(blockIdx.x & (NREP-1))*128 + tid], t);
    }
}

// ---------- k/q/v: m = blockIdx/128 selects matrix ----------
__global__ __launch_bounds__(256) void k_kqv(
    const float* __restrict__ t1,
    const float* __restrict__ Wk, const float* __restrict__ bk,
    const float* __restrict__ Wq, const float* __restrict__ bq,
    const float* __restrict__ Wv, const float* __restrict__ bv,
    const float* __restrict__ bnrep, const float* __restrict__ bng,
    const float* __restrict__ bnb,
    float* __restrict__ kout, float* __restrict__ qout, float* __restrict__ vout)
{
    __shared__ float Wl[CH*CH];
    __shared__ float bias[64];
    __shared__ float s_tmp[128];
    __shared__ float sc[64], sh[64];
    const int tid = threadIdx.x;
    const int m = blockIdx.x >> 7;
    const int rb = blockIdx.x & 127;
    const float* W  = (m==0) ? Wk : (m==1 ? Wq : Wv);
    const float* bs = (m==0) ? bk : (m==1 ? bq : bv);
    float* o        = (m==0) ? kout : (m==1 ? qout : vout);
    {
        const float4* W4 = (const float4*)W;
        float4* Wl4 = (float4*)Wl;
        #pragma unroll
        for (int i=0;i<4;++i) Wl4[i*256+tid] = W4[i*256+tid];
    }
    if (tid < 64) bias[tid] = bs[tid];
    LOAD_SCSH(bnrep, 1.f/NPTS, bng, bnb, sc, sh, 64);

    const int row = rb*256 + tid;
    float h[CH];
    {
        const float4* iv = (const float4*)(t1 + (size_t)row*CH);
        #pragma unroll
        for (int i=0;i<16;++i){ float4 t=iv[i];
            h[4*i]=t.x; h[4*i+1]=t.y; h[4*i+2]=t.z; h[4*i+3]=t.w; }
    }
    #pragma unroll
    for (int i=0;i<CH;++i) h[i] = frelu(h[i]*sc[i]+sh[i]);

    float4* ov = (float4*)(o + (size_t)row*CH);
    for (int cc=0; cc<16; ++cc){
        float4 acc = make_float4(bias[cc*4], bias[cc*4+1], bias[cc*4+2], bias[cc*4+3]);
        const float* w0=&Wl[(cc*4+0)*CH];
        const float* w1=&Wl[(cc*4+1)*CH];
        const float* w2=&Wl[(cc*4+2)*CH];
        const float* w3=&Wl[(cc*4+3)*CH];
        #pragma unroll
        for (int i=0;i<CH;++i){ float xv=h[i];
            acc.x+=xv*w0[i]; acc.y+=xv*w1[i]; acc.z+=xv*w2[i]; acc.w+=xv*w3[i]; }
        ov[cc]=acc;
    }
}

// ---------- w_bn1 stats over apre = k[src]-q[dst]+delta (lane = channel) ----------
__global__ __launch_bounds__(256) void k_edge1(
    const int* __restrict__ esrc, const float4* __restrict__ u4,
    const float* __restrict__ kbuf, const float* __restrict__ qbuf,
    const float* __restrict__ prep, const float* __restrict__ pg,
    const float* __restrict__ pb,
    const float* __restrict__ p2w, const float* __restrict__ p2b,
    float* __restrict__ gstat)
{
    __shared__ float red[4][128];
    __shared__ float s_tmp[128];
    __shared__ float scL[64], shL[64];
    const int tid = threadIdx.x;
    const int c = tid & 63, wv = tid >> 6;
    LOAD_SCSH(prep, 1.f/NE, pg, pb, scL, shL, 3);
    const float scp0=scL[0], scp1=scL[1], scp2=scL[2];
    const float shp0=shL[0], shp1=shL[1], shp2=shL[2];
    const float w0 = p2w[c*3+0], w1 = p2w[c*3+1], w2 = p2w[c*3+2], bc = p2b[c];

    const int gw = blockIdx.x*4 + wv;      // 8192 waves
    const int chunk = NE/8192;             // 64 edges/wave, contiguous (4 dst groups)
    const int e0 = gw*chunk;
    float s=0.f, q=0.f;
    #pragma unroll 4
    for (int e = e0; e < e0+chunk; ++e) {
        int sj = esrc[e]; int d = e >> 4;
        float4 uu = u4[e];
        float r0 = frelu(uu.x*scp0+shp0);
        float r1 = frelu(uu.y*scp1+shp1);
        float r2 = frelu(uu.z*scp2+shp2);
        float a = kbuf[(size_t)sj*CH+c] - qbuf[(size_t)d*CH+c]
                + (r0*w0 + r1*w1 + r2*w2 + bc);
        s += a; q += a*a;
    }
    red[wv][c] = s; red[wv][64+c] = q;
    __syncthreads();
    if (tid < 128) {
        float t = red[0][tid]+red[1][tid]+red[2][tid]+red[3][tid];
        atomicAdd(&gstat[(blockIdx.x & (NREP-1))*128 + tid], t);
    }
}

// ---------- a2 = relu(bn_w1(apre))@w1^T+b1 ; store ; w_bn2 stats (thread = edge) ----------
__global__ __launch_bounds__(256) void k_edge2(
    const int* __restrict__ esrc, const float4* __restrict__ u4,
    const float* __restrict__ kbuf, const float* __restrict__ qbuf,
    const float* __restrict__ prep, const float* __restrict__ pg,
    const float* __restrict__ pb,
    const float* __restrict__ p2w, const float* __restrict__ p2b,
    const float* __restrict__ w1rep, const float* __restrict__ w1g,
    const float* __restrict__ w1bn_b,
    const float* __restrict__ w1w, const float* __restrict__ w1bias,
    float* __restrict__ a2out, float* __restrict__ gstat)
{
    __shared__ float sp2w[192], sp2b[64], sw1[512], sw1b[8];
    __shared__ float s_tmp[128];
    __shared__ float scp[64], shp[64];
    __shared__ float sc1[64], sh1[64];
    __shared__ float red[4][16];
    const int tid = threadIdx.x;
    if (tid < 192) sp2w[tid] = p2w[tid];
    if (tid < 64)  sp2b[tid] = p2b[tid];
    sw1[tid] = w1w[tid]; sw1[256+tid] = w1w[256+tid];
    if (tid < 8) sw1b[tid] = w1bias[tid];
    LOAD_SCSH(prep, 1.f/NE, pg, pb, scp, shp, 3);
    LOAD_SCSH(w1rep, 1.f/NE, w1g, w1bn_b, sc1, sh1, 64);
    const float scp0=scp[0], scp1=scp[1], scp2=scp[2];
    const float shp0=shp[0], shp1=shp[1], shp2=shp[2];

    float s8[8] = {0,0,0,0,0,0,0,0}, q8[8] = {0,0,0,0,0,0,0,0};
    for (int e = blockIdx.x*256 + tid; e < NE; e += 1024*256) {
        const int sj = esrc[e]; const int d = e >> 4;
        float4 uu = u4[e];
        const float r0 = frelu(uu.x*scp0+shp0);
        const float r1 = frelu(uu.y*scp1+shp1);
        const float r2 = frelu(uu.z*scp2+shp2);
        const float4* kv = (const float4*)(kbuf + (size_t)sj*CH);
        const float4* qv = (const float4*)(qbuf + (size_t)d*CH);
        float a2a[8];
        #pragma unroll
        for (int j=0;j<8;++j) a2a[j] = sw1b[j];
        for (int cc=0; cc<16; ++cc) {
            float4 k4 = kv[cc], q4 = qv[cc];
            const int c0 = cc*4;
            float b0 = frelu((k4.x - q4.x + r0*sp2w[(c0+0)*3]+r1*sp2w[(c0+0)*3+1]+r2*sp2w[(c0+0)*3+2]+sp2b[c0+0])*sc1[c0+0]+sh1[c0+0]);
            float b1 = frelu((k4.y - q4.y + r0*sp2w[(c0+1)*3]+r1*sp2w[(c0+1)*3+1]+r2*sp2w[(c0+1)*3+2]+sp2b[c0+1])*sc1[c0+1]+sh1[c0+1]);
            float b2 = frelu((k4.z - q4.z + r0*sp2w[(c0+2)*3]+r1*sp2w[(c0+2)*3+1]+r2*sp2w[(c0+2)*3+2]+sp2b[c0+2])*sc1[c0+2]+sh1[c0+2]);
            float b3 = frelu((k4.w - q4.w + r0*sp2w[(c0+3)*3]+r1*sp2w[(c0+3)*3+1]+r2*sp2w[(c0+3)*3+2]+sp2b[c0+3])*sc1[c0+3]+sh1[c0+3]);
            #pragma unroll
            for (int j=0;j<8;++j)
                a2a[j] += b0*sw1[j*64+c0] + b1*sw1[j*64+c0+1] + b2*sw1[j*64+c0+2] + b3*sw1[j*64+c0+3];
        }
        float4* a2v = (float4*)(a2out + (size_t)e*8);
        a2v[0] = make_float4(a2a[0],a2a[1],a2a[2],a2a[3]);
        a2v[1] = make_float4(a2a[4],a2a[5],a2a[6],a2a[7]);
        #pragma unroll
        for (int j=0;j<8;++j){ s8[j]+=a2a[j]; q8[j]+=a2a[j]*a2a[j]; }
    }
    #pragma unroll
    for (int m=32;m>=1;m>>=1){
        #pragma unroll
        for (int j=0;j<8;++j){ s8[j]+=__shfl_xor(s8[j],m); q8[j]+=__shfl_xor(q8[j],m); }
    }
    const int wv = tid>>6;
    if ((tid&63)==0){
        #pragma unroll
        for (int j=0;j<8;++j){ red[wv][j]=s8[j]; red[wv][8+j]=q8[j]; }
    }
    __syncthreads();
    if (tid < 16) {
        float t = red[0][tid]+red[1][tid]+red[2][tid]+red[3][tid];
        int dstc = (tid<8) ? tid : (64 + tid - 8);
        atomicAdd(&gstat[(blockIdx.x & (NREP-1))*128 + dstc], t);
    }
}

// ---------- bn_w2 + w2 matmul + 16-way softmax + weighted aggregation + bn2 stats ----------
__global__ __launch_bounds__(256) void k_attn(
    const int* __restrict__ esrc, const float4* __restrict__ u4,
    const float* __restrict__ vbuf, const float* __restrict__ a2buf,
    const float* __restrict__ prep, const float* __restrict__ pg,
    const float* __restrict__ pb,
    const float* __restrict__ p2w, const float* __restrict__ p2b,
    const float* __restrict__ w2rep, const float* __restrict__ w2g,
    const float* __restrict__ w2bn_b,
    const float* __restrict__ w2w, const float* __restrict__ w2bias,
    float* __restrict__ outbuf, float* __restrict__ gstat)
{
    __shared__ float sp2w[192], sp2b[64], sw2[64], sw2b[8];
    __shared__ float s_tmp[128];
    __shared__ float scp[64], shp[64];
    __shared__ float sc2[64], sh2[64];
    __shared__ float red[4][128];
    const int tid = threadIdx.x;
    if (tid < 192) sp2w[tid] = p2w[tid];
    if (tid < 64) { sp2b[tid] = p2b[tid]; sw2[tid] = w2w[tid]; }
    if (tid < 8)  sw2b[tid] = w2bias[tid];
    LOAD_SCSH(prep, 1.f/NE, pg, pb, scp, shp, 3);
    LOAD_SCSH(w2rep, 1.f/NE, w2g, w2bn_b, sc2, sh2, 8);
    const float scp0=scp[0], scp1=scp[1], scp2=scp[2];
    const float shp0=shp[0], shp1=shp[1], shp2=shp[2];

    const int t = tid & 15;
    const int i = blockIdx.x*16 + (tid>>4);
    const int e = i*KNN + t;
    const int sj = esrc[e];

    const float4* a2v = (const float4*)a2buf;
    float4 aA = a2v[(size_t)e*2], aB = a2v[(size_t)e*2+1];
    float bb[8];
    bb[0]=frelu(aA.x*sc2[0]+sh2[0]); bb[1]=frelu(aA.y*sc2[1]+sh2[1]);
    bb[2]=frelu(aA.z*sc2[2]+sh2[2]); bb[3]=frelu(aA.w*sc2[3]+sh2[3]);
    bb[4]=frelu(aB.x*sc2[4]+sh2[4]); bb[5]=frelu(aB.y*sc2[5]+sh2[5]);
    bb[6]=frelu(aB.z*sc2[6]+sh2[6]); bb[7]=frelu(aB.w*sc2[7]+sh2[7]);
    float attn[8];
    #pragma unroll
    for (int s=0;s<8;++s){
        float a3 = sw2b[s];
        #pragma unroll
        for (int u=0;u<8;++u) a3 += bb[u]*sw2[s*8+u];
        attn[s]=a3;
    }
    #pragma unroll
    for (int s=0;s<8;++s){
        float m = attn[s];
        #pragma unroll
        for (int msk=8;msk>=1;msk>>=1) m = fmaxf(m, __shfl_xor(m,msk));
        float p = __expf(attn[s]-m);
        float ssm = p;
        #pragma unroll
        for (int msk=8;msk>=1;msk>>=1) ssm += __shfl_xor(ssm,msk);
        attn[s] = p/ssm;
    }
    float4 uu = u4[e];
    const float r0 = frelu(uu.x*scp0+shp0);
    const float r1 = frelu(uu.y*scp1+shp1);
    const float r2 = frelu(uu.z*scp2+shp2);
    const float4* vv = (const float4*)(vbuf + (size_t)sj*CH);
    float4 res = make_float4(0,0,0,0);
    for (int cc=0; cc<16; ++cc){
        float4 v4 = vv[cc];
        const int c0 = cc*4;
        float d0 = r0*sp2w[(c0+0)*3]+r1*sp2w[(c0+0)*3+1]+r2*sp2w[(c0+0)*3+2]+sp2b[c0+0];
        float d1 = r0*sp2w[(c0+1)*3]+r1*sp2w[(c0+1)*3+1]+r2*sp2w[(c0+1)*3+2]+sp2b[c0+1];
        float d2 = r0*sp2w[(c0+2)*3]+r1*sp2w[(c0+2)*3+1]+r2*sp2w[(c0+2)*3+2]+sp2b[c0+2];
        float d3 = r0*sp2w[(c0+3)*3]+r1*sp2w[(c0+3)*3+1]+r2*sp2w[(c0+3)*3+2]+sp2b[c0+3];
        const int sb = (cc&1)*4;
        float m0 = attn[sb+0]*(v4.x+d0);
        float m1 = attn[sb+1]*(v4.y+d1);
        float m2 = attn[sb+2]*(v4.z+d2);
        float m3 = attn[sb+3]*(v4.w+d3);
        #pragma unroll
        for (int msk=8;msk>=1;msk>>=1){
            m0+=__shfl_xor(m0,msk); m1+=__shfl_xor(m1,msk);
            m2+=__shfl_xor(m2,msk); m3+=__shfl_xor(m3,msk);
        }
        if (t == cc) res = make_float4(m0,m1,m2,m3);
    }
    ((float4*)outbuf)[(size_t)i*16 + t] = res;

    // fused bn2 stats: thread holds channels 4t..4t+3 of point i
    float4 sq = make_float4(res.x*res.x, res.y*res.y, res.z*res.z, res.w*res.w);
    #pragma unroll
    for (int msk=32;msk>=16;msk>>=1){
        res.x+=__shfl_xor(res.x,msk); res.y+=__shfl_xor(res.y,msk);
        res.z+=__shfl_xor(res.z,msk); res.w+=__shfl_xor(res.w,msk);
        sq.x+=__shfl_xor(sq.x,msk);  sq.y+=__shfl_xor(sq.y,msk);
        sq.z+=__shfl_xor(sq.z,msk);  sq.w+=__shfl_xor(sq.w,msk);
    }
    const int wv = tid>>6;
    if ((tid&63) < 16){
        red[wv][t*4+0]=res.x; red[wv][t*4+1]=res.y; red[wv][t*4+2]=res.z; red[wv][t*4+3]=res.w;
        red[wv][64+t*4+0]=sq.x; red[wv][64+t*4+1]=sq.y; red[wv][64+t*4+2]=sq.z; red[wv][64+t*4+3]=sq.w;
    }
    __syncthreads();
    if (tid < 128) {
        float tt = red[0][tid]+red[1][tid]+red[2][tid]+red[3][tid];
        atomicAdd(&gstat[(blockIdx.x & (NREP-1))*128 + tid], tt);
    }
}

// ---------- final = relu(bn3(h3) + x_skip) ----------
__global__ __launch_bounds__(256) void k_final(
    const float* __restrict__ h3, const float* __restrict__ x,
    const float* __restrict__ bnrep, const float* __restrict__ g,
    const float* __restrict__ b, float* __restrict__ out)
{
    __shared__ float s_tmp[128];
    __shared__ float sc[64], sh[64];
    const int tid = threadIdx.x;
    LOAD_SCSH(bnrep, 1.f/NPTS, g, b, sc, sh, 64);
    const int gi = blockIdx.x*256 + tid;
    const int c0 = (gi & 15)*4;
    float4 h = ((const float4*)h3)[gi];
    float4 xv = ((const float4*)x)[gi];
    float4 o;
    o.x = fmaxf(h.x*sc[c0+0]+sh[c0+0]+xv.x, 0.f);
    o.y = fmaxf(h.y*sc[c0+1]+sh[c0+1]+xv.y, 0.f);
    o.z = fmaxf(h.z*sc[c0+2]+sh[c0+2]+xv.z, 0.f);
    o.w = fmaxf(h.w*sc[c0+3]+sh[c0+3]+xv.w, 0.f);
    ((float4*)out)[gi] = o;
}

extern "C" void kernel_launch(void* const* d_in, const int* in_sizes, int n_in,
                              void* d_out, int out_size, void* d_ws, size_t ws_size,
                              hipStream_t stream) {
    (void)in_sizes; (void)n_in; (void)out_size; (void)ws_size;
    const float* pos   = (const float*)d_in[0];
    const float* x     = (const float*)d_in[1];
    const float* W1    = (const float*)d_in[2];
    const float* Wk    = (const float*)d_in[3];
    const float* bk    = (const float*)d_in[4];
    const float* Wq    = (const float*)d_in[5];
    const float* bq    = (const float*)d_in[6];
    const float* Wv    = (const float*)d_in[7];
    const float* bv    = (const float*)d_in[8];
    const float* p1w   = (const float*)d_in[9];
    const float* p1b   = (const float*)d_in[10];
    const float* pg    = (const float*)d_in[11];
    const float* pb    = (const float*)d_in[12];
    const float* p2w   = (const float*)d_in[13];
    const float* p2b   = (const float*)d_in[14];
    const float* w1g   = (const float*)d_in[15];
    const float* w1bb  = (const float*)d_in[16];
    const float* w1w   = (const float*)d_in[17];
    const float* w1bias= (const float*)d_in[18];
    const float* w2g   = (const float*)d_in[19];
    const float* w2bb  = (const float*)d_in[20];
    const float* w2w   = (const float*)d_in[21];
    const float* w2bias= (const float*)d_in[22];
    const float* W3    = (const float*)d_in[23];
    const float* bn1g  = (const float*)d_in[24];
    const float* bn1b  = (const float*)d_in[25];
    const float* bn2g  = (const float*)d_in[26];
    const float* bn2b  = (const float*)d_in[27];
    const float* bn3g  = (const float*)d_in[28];
    const float* bn3b  = (const float*)d_in[29];
    const int*   ei    = (const int*)d_in[30];
    float* ws  = (float*)d_ws;
    float* out = (float*)d_out;

    hipMemsetAsync(ws, 0, STATS_FLOATS*sizeof(float), stream);

    // u precompute + p-bn stats (independent of GEMM chain)
    k_pstats_u<<<1024, 256, 0, stream>>>(pos, ei, p1w, p1b,
        (float4*)(ws+OFF_U), ws+G_P);
    // t1 = x @ W1^T + bn1 stats
    k_gemm64<<<128, 256, 0, stream>>>(x, W1, ws+OFF_T1,
        nullptr, nullptr, nullptr, 0, ws+G_BN1);
    // k,q,v
    k_kqv<<<384, 256, 0, stream>>>(ws+OFF_T1, Wk, bk, Wq, bq, Wv, bv,
        ws+G_BN1, bn1g, bn1b, ws+OFF_K, ws+OFF_Q, ws+OFF_V);
    // w_bn1 stats
    k_edge1<<<2048, 256, 0, stream>>>(ei, (const float4*)(ws+OFF_U),
        ws+OFF_K, ws+OFF_Q, ws+G_P, pg, pb, p2w, p2b, ws+G_W1);
    // a2 + w_bn2 stats
    k_edge2<<<1024, 256, 0, stream>>>(ei, (const float4*)(ws+OFF_U),
        ws+OFF_K, ws+OFF_Q, ws+G_P, pg, pb, p2w, p2b,
        ws+G_W1, w1g, w1bb, w1w, w1bias, ws+OFF_A2, ws+G_W2);
    // softmax + aggregate + bn2 stats
    k_attn<<<2048, 256, 0, stream>>>(ei, (const float4*)(ws+OFF_U),
        ws+OFF_V, ws+OFF_A2, ws+G_P, pg, pb, p2w, p2b,
        ws+G_W2, w2g, w2bb, w2w, w2bias, ws+OFF_OUT, ws+G_BN2);
    // h3 = relu(bn2(out)) @ W3^T + bn3 stats
    k_gemm64<<<128, 256, 0, stream>>>(ws+OFF_OUT, W3, ws+OFF_H3,
        ws+G_BN2, bn2g, bn2b, 1, ws+G_BN3);
    // final
    k_final<<<2048, 256, 0, stream>>>(ws+OFF_H3, x, ws+G_BN3, bn3g, bn3b, out);
}

// Round 4
// 311.513 us; speedup vs baseline: 3.1719x; 1.1783x over previous
//
#include <hip/hip_runtime.h>

#define NPTS 32768
#define CH 64
#define KNN 16
#define NE (NPTS*KNN)
#define EPS 1e-5f
#define NREP 32

// stats groups: NREP replicas x 128 floats; sums at [c], sumsq at [64+c]
#define G_P   0
#define G_BN1 (1*NREP*128)
#define G_W1  (2*NREP*128)
#define G_W2  (3*NREP*128)
#define G_BN2 (4*NREP*128)
#define G_BN3 (5*NREP*128)
#define STATS_FLOATS (6*NREP*128)

#define OFF_T1  (STATS_FLOATS + 512)
#define SZ_NC   (NPTS*CH)
#define OFF_K   (OFF_T1 + SZ_NC)
#define OFF_Q   (OFF_K + SZ_NC)
#define OFF_V   (OFF_Q + SZ_NC)
#define OFF_A2  (OFF_V + SZ_NC)
#define OFF_OUT (OFF_A2 + NE*8)
#define OFF_U   (OFF_OUT + SZ_NC)   /* NE*4 floats; shared with H3 (dead by then) */
#define OFF_H3  OFF_U

__device__ __forceinline__ float frelu(float x){ return fmaxf(x, 0.f); }

// reduce a stats group (NREP x 128) and produce scale/shift in LDS arrays (nch<=64)
#define LOAD_SCSH(grp, invc, gptr, bptr, scA, shA, nch) do {                        \
    if (tid < 128) { float t_ = 0.f;                                                \
        _Pragma("unroll") for (int r_ = 0; r_ < NREP; ++r_) t_ += (grp)[r_*128+tid];\
        s_tmp[tid] = t_; }                                                          \
    __syncthreads();                                                                \
    if (tid < (nch)) { float m_ = s_tmp[tid]*(invc);                                \
        float v_ = s_tmp[64+tid]*(invc) - m_*m_;                                    \
        float s_ = (gptr)[tid]*rsqrtf(v_+EPS);                                      \
        (scA)[tid] = s_; (shA)[tid] = (bptr)[tid] - m_*s_; }                        \
    __syncthreads();                                                                \
} while(0)

// ---------- u = rel @ p1_w^T + p1_b per edge (stored), plus p-bn stats ----------
__global__ __launch_bounds__(256) void k_pstats_u(
    const float* __restrict__ pos, const int* __restrict__ esrc,
    const float* __restrict__ p1w, const float* __restrict__ p1b,
    float4* __restrict__ u4, float* __restrict__ gstat)
{
    __shared__ float red[4][6];
    const int tid = threadIdx.x;
    float w[9], b3[3];
    #pragma unroll
    for (int i=0;i<9;++i) w[i]=p1w[i];
    b3[0]=p1b[0]; b3[1]=p1b[1]; b3[2]=p1b[2];
    const int e = blockIdx.x*256 + tid;    // 2048 blocks: exactly one edge/thread
    const int sj = esrc[e]; const int d = e >> 4;
    float ax = pos[3*sj]-pos[3*d], ay = pos[3*sj+1]-pos[3*d+1], az = pos[3*sj+2]-pos[3*d+2];
    float u0 = w[0]*ax+w[1]*ay+w[2]*az+b3[0];
    float u1 = w[3]*ax+w[4]*ay+w[5]*az+b3[1];
    float u2 = w[6]*ax+w[7]*ay+w[8]*az+b3[2];
    u4[e] = make_float4(u0,u1,u2,0.f);
    float s0=u0,s1=u1,s2=u2,q0=u0*u0,q1=u1*u1,q2=u2*u2;
    #pragma unroll
    for (int m=32;m>=1;m>>=1){
        s0+=__shfl_xor(s0,m); s1+=__shfl_xor(s1,m); s2+=__shfl_xor(s2,m);
        q0+=__shfl_xor(q0,m); q1+=__shfl_xor(q1,m); q2+=__shfl_xor(q2,m);
    }
    const int wv = tid>>6;
    if ((tid&63)==0){ red[wv][0]=s0; red[wv][1]=s1; red[wv][2]=s2;
                      red[wv][3]=q0; red[wv][4]=q1; red[wv][5]=q2; }
    __syncthreads();
    float* g = gstat + (blockIdx.x & (NREP-1))*128;
    if (tid < 3)      atomicAdd(&g[tid],        red[0][tid]+red[1][tid]+red[2][tid]+red[3][tid]);
    else if (tid < 6) atomicAdd(&g[64+(tid-3)], red[0][tid]+red[1][tid]+red[2][tid]+red[3][tid]);
}

// ---------- [N,64]@W^T, sliced 16 out-channels/block, fused output stats ----------
// grid: 512; by = bid>>7 selects channel slice, rb = bid&127 selects 256 rows
__global__ __launch_bounds__(256) void k_gemm64(
    const float* __restrict__ in, const float* __restrict__ W,
    float* __restrict__ out,
    const float* __restrict__ bnrep, const float* __restrict__ bng,
    const float* __restrict__ bnb, int applyBn,
    float* __restrict__ gstat)
{
    __shared__ float Wl[16*CH];
    __shared__ float s_tmp[128];
    __shared__ float sc[64], sh[64];
    __shared__ float red[4][32];
    const int tid = threadIdx.x;
    const int wv = tid >> 6;
    const int by = blockIdx.x >> 7;
    const int rb = blockIdx.x & 127;
    const int c0 = by*16;
    ((float4*)Wl)[tid] = ((const float4*)(W + c0*CH))[tid];
    if (applyBn) { LOAD_SCSH(bnrep, 1.f/NPTS, bng, bnb, sc, sh, 64); }
    else __syncthreads();

    const int row = rb*256 + tid;
    float xr[CH];
    {
        const float4* iv = (const float4*)(in + (size_t)row*CH);
        #pragma unroll
        for (int i=0;i<16;++i){ float4 t=iv[i];
            xr[4*i]=t.x; xr[4*i+1]=t.y; xr[4*i+2]=t.z; xr[4*i+3]=t.w; }
    }
    if (applyBn){
        #pragma unroll
        for (int i=0;i<CH;++i) xr[i] = frelu(xr[i]*sc[i]+sh[i]);
    }
    float4* ov = (float4*)(out + (size_t)row*CH + c0);
    #pragma unroll
    for (int q=0; q<4; ++q){
        float4 acc = make_float4(0,0,0,0);
        const float* w0=&Wl[(q*4+0)*CH];
        const float* w1=&Wl[(q*4+1)*CH];
        const float* w2=&Wl[(q*4+2)*CH];
        const float* w3=&Wl[(q*4+3)*CH];
        #pragma unroll
        for (int i=0;i<CH;++i){ float xv=xr[i];
            acc.x+=xv*w0[i]; acc.y+=xv*w1[i]; acc.z+=xv*w2[i]; acc.w+=xv*w3[i]; }
        ov[q]=acc;
        float4 sq = make_float4(acc.x*acc.x, acc.y*acc.y, acc.z*acc.z, acc.w*acc.w);
        #pragma unroll
        for (int m=32;m>=1;m>>=1){
            acc.x+=__shfl_xor(acc.x,m); acc.y+=__shfl_xor(acc.y,m);
            acc.z+=__shfl_xor(acc.z,m); acc.w+=__shfl_xor(acc.w,m);
            sq.x+=__shfl_xor(sq.x,m);  sq.y+=__shfl_xor(sq.y,m);
            sq.z+=__shfl_xor(sq.z,m);  sq.w+=__shfl_xor(sq.w,m);
        }
        if ((tid&63)==0){
            red[wv][q*4+0]=acc.x; red[wv][q*4+1]=acc.y; red[wv][q*4+2]=acc.z; red[wv][q*4+3]=acc.w;
            red[wv][16+q*4+0]=sq.x; red[wv][16+q*4+1]=sq.y; red[wv][16+q*4+2]=sq.z; red[wv][16+q*4+3]=sq.w;
        }
    }
    __syncthreads();
    if (tid < 32) {
        float t = red[0][tid]+red[1][tid]+red[2][tid]+red[3][tid];
        int dstc = (tid<16) ? (c0+tid) : (64 + c0 + (tid-16));
        atomicAdd(&gstat[(blockIdx.x & (NREP-1))*128 + dstc], t);
    }
}

// ---------- k/q/v: grid 768; m=bid/256, rb=(bid%256)>>1, half=(bid%256)&1 ----------
__global__ __launch_bounds__(256) void k_kqv(
    const float* __restrict__ t1,
    const float* __restrict__ Wk, const float* __restrict__ bk,
    const float* __restrict__ Wq, const float* __restrict__ bq,
    const float* __restrict__ Wv, const float* __restrict__ bv,
    const float* __restrict__ bnrep, const float* __restrict__ bng,
    const float* __restrict__ bnb,
    float* __restrict__ kout, float* __restrict__ qout, float* __restrict__ vout)
{
    __shared__ float Wl[32*CH];
    __shared__ float bias[32];
    __shared__ float s_tmp[128];
    __shared__ float sc[64], sh[64];
    const int tid = threadIdx.x;
    const int m = blockIdx.x / 256;
    const int rem = blockIdx.x & 255;
    const int rb = rem >> 1;
    const int cbase = (rem & 1)*32;
    const float* W  = (m==0) ? Wk : (m==1 ? Wq : Wv);
    const float* bs = (m==0) ? bk : (m==1 ? bq : bv);
    float* o        = (m==0) ? kout : (m==1 ? qout : vout);
    {
        const float4* W4 = (const float4*)(W + cbase*CH);
        float4* Wl4 = (float4*)Wl;
        Wl4[tid] = W4[tid]; Wl4[256+tid] = W4[256+tid];
    }
    if (tid < 32) bias[tid] = bs[cbase+tid];
    LOAD_SCSH(bnrep, 1.f/NPTS, bng, bnb, sc, sh, 64);

    const int row = rb*256 + tid;
    float h[CH];
    {
        const float4* iv = (const float4*)(t1 + (size_t)row*CH);
        #pragma unroll
        for (int i=0;i<16;++i){ float4 t=iv[i];
            h[4*i]=t.x; h[4*i+1]=t.y; h[4*i+2]=t.z; h[4*i+3]=t.w; }
    }
    #pragma unroll
    for (int i=0;i<CH;++i) h[i] = frelu(h[i]*sc[i]+sh[i]);

    float4* ov = (float4*)(o + (size_t)row*CH + cbase);
    #pragma unroll
    for (int q=0; q<8; ++q){
        float4 acc = make_float4(bias[q*4], bias[q*4+1], bias[q*4+2], bias[q*4+3]);
        const float* w0=&Wl[(q*4+0)*CH];
        const float* w1=&Wl[(q*4+1)*CH];
        const float* w2=&Wl[(q*4+2)*CH];
        const float* w3=&Wl[(q*4+3)*CH];
        #pragma unroll
        for (int i=0;i<CH;++i){ float xv=h[i];
            acc.x+=xv*w0[i]; acc.y+=xv*w1[i]; acc.z+=xv*w2[i]; acc.w+=xv*w3[i]; }
        ov[q]=acc;
    }
}

// ---------- w_bn1 stats over apre = k[src]-q[dst]+delta (lane = channel) ----------
__global__ __launch_bounds__(256) void k_edge1(
    const int* __restrict__ esrc, const float4* __restrict__ u4,
    const float* __restrict__ kbuf, const float* __restrict__ qbuf,
    const float* __restrict__ prep, const float* __restrict__ pg,
    const float* __restrict__ pb,
    const float* __restrict__ p2w, const float* __restrict__ p2b,
    float* __restrict__ gstat)
{
    __shared__ float red[4][128];
    __shared__ float s_tmp[128];
    __shared__ float scL[64], shL[64];
    const int tid = threadIdx.x;
    const int c = tid & 63, wv = tid >> 6;
    LOAD_SCSH(prep, 1.f/NE, pg, pb, scL, shL, 3);
    const float scp0=scL[0], scp1=scL[1], scp2=scL[2];
    const float shp0=shL[0], shp1=shL[1], shp2=shL[2];
    const float w0 = p2w[c*3+0], w1 = p2w[c*3+1], w2 = p2w[c*3+2], bc = p2b[c];

    const int gw = blockIdx.x*4 + wv;      // 8192 waves
    const int chunk = NE/8192;             // 64 edges/wave, contiguous (4 dst groups)
    const int e0 = gw*chunk;
    float s=0.f, q=0.f;
    #pragma unroll 4
    for (int e = e0; e < e0+chunk; ++e) {
        int sj = esrc[e]; int d = e >> 4;
        float4 uu = u4[e];
        float r0 = frelu(uu.x*scp0+shp0);
        float r1 = frelu(uu.y*scp1+shp1);
        float r2 = frelu(uu.z*scp2+shp2);
        float a = kbuf[(size_t)sj*CH+c] - qbuf[(size_t)d*CH+c]
                + (r0*w0 + r1*w1 + r2*w2 + bc);
        s += a; q += a*a;
    }
    red[wv][c] = s; red[wv][64+c] = q;
    __syncthreads();
    if (tid < 128) {
        float t = red[0][tid]+red[1][tid]+red[2][tid]+red[3][tid];
        atomicAdd(&gstat[(blockIdx.x & (NREP-1))*128 + tid], t);
    }
}

// ---------- a2 = relu(bn_w1(apre))@w1^T+b1 ; store ; w_bn2 stats (thread = edge, 2048 blocks) ----------
__global__ __launch_bounds__(256) void k_edge2(
    const int* __restrict__ esrc, const float4* __restrict__ u4,
    const float* __restrict__ kbuf, const float* __restrict__ qbuf,
    const float* __restrict__ prep, const float* __restrict__ pg,
    const float* __restrict__ pb,
    const float* __restrict__ p2w, const float* __restrict__ p2b,
    const float* __restrict__ w1rep, const float* __restrict__ w1g,
    const float* __restrict__ w1bn_b,
    const float* __restrict__ w1w, const float* __restrict__ w1bias,
    float* __restrict__ a2out, float* __restrict__ gstat)
{
    __shared__ float sp2w[192], sp2b[64], sw1[512], sw1b[8];
    __shared__ float s_tmp[128];
    __shared__ float scp[64], shp[64];
    __shared__ float sc1[64], sh1[64];
    __shared__ float red[4][16];
    const int tid = threadIdx.x;
    if (tid < 192) sp2w[tid] = p2w[tid];
    if (tid < 64)  sp2b[tid] = p2b[tid];
    sw1[tid] = w1w[tid]; sw1[256+tid] = w1w[256+tid];
    if (tid < 8) sw1b[tid] = w1bias[tid];
    LOAD_SCSH(prep, 1.f/NE, pg, pb, scp, shp, 3);
    LOAD_SCSH(w1rep, 1.f/NE, w1g, w1bn_b, sc1, sh1, 64);
    const float scp0=scp[0], scp1=scp[1], scp2=scp[2];
    const float shp0=shp[0], shp1=shp[1], shp2=shp[2];

    const int e = blockIdx.x*256 + tid;    // 2048 blocks, one edge/thread
    const int sj = esrc[e]; const int d = e >> 4;
    float4 uu = u4[e];
    const float r0 = frelu(uu.x*scp0+shp0);
    const float r1 = frelu(uu.y*scp1+shp1);
    const float r2 = frelu(uu.z*scp2+shp2);
    const float4* kv = (const float4*)(kbuf + (size_t)sj*CH);
    const float4* qv = (const float4*)(qbuf + (size_t)d*CH);
    float a2a[8];
    #pragma unroll
    for (int j=0;j<8;++j) a2a[j] = sw1b[j];
    for (int cc=0; cc<16; ++cc) {
        float4 k4 = kv[cc], q4 = qv[cc];
        const int c0 = cc*4;
        float b0 = frelu((k4.x - q4.x + r0*sp2w[(c0+0)*3]+r1*sp2w[(c0+0)*3+1]+r2*sp2w[(c0+0)*3+2]+sp2b[c0+0])*sc1[c0+0]+sh1[c0+0]);
        float b1 = frelu((k4.y - q4.y + r0*sp2w[(c0+1)*3]+r1*sp2w[(c0+1)*3+1]+r2*sp2w[(c0+1)*3+2]+sp2b[c0+1])*sc1[c0+1]+sh1[c0+1]);
        float b2 = frelu((k4.z - q4.z + r0*sp2w[(c0+2)*3]+r1*sp2w[(c0+2)*3+1]+r2*sp2w[(c0+2)*3+2]+sp2b[c0+2])*sc1[c0+2]+sh1[c0+2]);
        float b3 = frelu((k4.w - q4.w + r0*sp2w[(c0+3)*3]+r1*sp2w[(c0+3)*3+1]+r2*sp2w[(c0+3)*3+2]+sp2b[c0+3])*sc1[c0+3]+sh1[c0+3]);
        #pragma unroll
        for (int j=0;j<8;++j)
            a2a[j] += b0*sw1[j*64+c0] + b1*sw1[j*64+c0+1] + b2*sw1[j*64+c0+2] + b3*sw1[j*64+c0+3];
    }
    float4* a2v = (float4*)(a2out + (size_t)e*8);
    a2v[0] = make_float4(a2a[0],a2a[1],a2a[2],a2a[3]);
    a2v[1] = make_float4(a2a[4],a2a[5],a2a[6],a2a[7]);
    float q8[8];
    #pragma unroll
    for (int j=0;j<8;++j) q8[j]=a2a[j]*a2a[j];
    #pragma unroll
    for (int m=32;m>=1;m>>=1){
        #pragma unroll
        for (int j=0;j<8;++j){ a2a[j]+=__shfl_xor(a2a[j],m); q8[j]+=__shfl_xor(q8[j],m); }
    }
    const int wv = tid>>6;
    if ((tid&63)==0){
        #pragma unroll
        for (int j=0;j<8;++j){ red[wv][j]=a2a[j]; red[wv][8+j]=q8[j]; }
    }
    __syncthreads();
    if (tid < 16) {
        float t = red[0][tid]+red[1][tid]+red[2][tid]+red[3][tid];
        int dstc = (tid<8) ? tid : (64 + tid - 8);
        atomicAdd(&gstat[(blockIdx.x & (NREP-1))*128 + dstc], t);
    }
}

// ---------- bn_w2 + w2 matmul + softmax (phase A), channel-owner aggregation (phase B) + bn2 stats ----------
__global__ __launch_bounds__(256) void k_attn(
    const int* __restrict__ esrc, const float4* __restrict__ u4,
    const float* __restrict__ vbuf, const float* __restrict__ a2buf,
    const float* __restrict__ prep, const float* __restrict__ pg,
    const float* __restrict__ pb,
    const float* __restrict__ p2w, const float* __restrict__ p2b,
    const float* __restrict__ w2rep, const float* __restrict__ w2g,
    const float* __restrict__ w2bn_b,
    const float* __restrict__ w2w, const float* __restrict__ w2bias,
    float* __restrict__ outbuf, float* __restrict__ gstat)
{
    __shared__ float sp2w[192], sp2b[64], sw2[64], sw2b[8];
    __shared__ float s_tmp[128];
    __shared__ float scp[64], shp[64];
    __shared__ float sc2[64], sh2[64];
    __shared__ float red[4][128];
    __shared__ float att[256][9];     // pad 9 to break bank conflicts
    __shared__ float rrL[256][4];
    __shared__ int   sjL[256];
    const int tid = threadIdx.x;
    if (tid < 192) sp2w[tid] = p2w[tid];
    if (tid < 64) { sp2b[tid] = p2b[tid]; sw2[tid] = w2w[tid]; }
    if (tid < 8)  sw2b[tid] = w2bias[tid];
    LOAD_SCSH(prep, 1.f/NE, pg, pb, scp, shp, 3);
    LOAD_SCSH(w2rep, 1.f/NE, w2g, w2bn_b, sc2, sh2, 8);
    const float scp0=scp[0], scp1=scp[1], scp2=scp[2];
    const float shp0=shp[0], shp1=shp[1], shp2=shp[2];

    const int t = tid & 15;
    const int i = blockIdx.x*16 + (tid>>4);
    const int e = i*KNN + t;
    const int sj = esrc[e];
    sjL[tid] = sj;
    {
        float4 uu = u4[e];
        rrL[tid][0] = frelu(uu.x*scp0+shp0);
        rrL[tid][1] = frelu(uu.y*scp1+shp1);
        rrL[tid][2] = frelu(uu.z*scp2+shp2);
    }
    // ---- phase A: logits + 16-way softmax, stage attn in LDS ----
    {
        const float4* a2v = (const float4*)a2buf;
        float4 aA = a2v[(size_t)e*2], aB = a2v[(size_t)e*2+1];
        float bb[8];
        bb[0]=frelu(aA.x*sc2[0]+sh2[0]); bb[1]=frelu(aA.y*sc2[1]+sh2[1]);
        bb[2]=frelu(aA.z*sc2[2]+sh2[2]); bb[3]=frelu(aA.w*sc2[3]+sh2[3]);
        bb[4]=frelu(aB.x*sc2[4]+sh2[4]); bb[5]=frelu(aB.y*sc2[5]+sh2[5]);
        bb[6]=frelu(aB.z*sc2[6]+sh2[6]); bb[7]=frelu(aB.w*sc2[7]+sh2[7]);
        #pragma unroll
        for (int s=0;s<8;++s){
            float a3 = sw2b[s];
            #pragma unroll
            for (int u=0;u<8;++u) a3 += bb[u]*sw2[s*8+u];
            float m = a3;
            #pragma unroll
            for (int msk=8;msk>=1;msk>>=1) m = fmaxf(m, __shfl_xor(m,msk));
            float p = __expf(a3-m);
            float ssm = p;
            #pragma unroll
            for (int msk=8;msk>=1;msk>>=1) ssm += __shfl_xor(ssm,msk);
            att[tid][s] = p/ssm;
        }
    }
    __syncthreads();
    // ---- phase B: thread owns channels 4t..4t+3 of point i, loops 16 neighbors ----
    const int base = (tid>>4)*16;   // block-local edge group for point i
    const int c0 = 4*t;
    const int ho = (t&1)*4;         // attn channel offset = c0 % 8
    const float pw00=sp2w[(c0+0)*3], pw01=sp2w[(c0+0)*3+1], pw02=sp2w[(c0+0)*3+2], pb0=sp2b[c0+0];
    const float pw10=sp2w[(c0+1)*3], pw11=sp2w[(c0+1)*3+1], pw12=sp2w[(c0+1)*3+2], pb1=sp2b[c0+1];
    const float pw20=sp2w[(c0+2)*3], pw21=sp2w[(c0+2)*3+1], pw22=sp2w[(c0+2)*3+2], pb2=sp2b[c0+2];
    const float pw30=sp2w[(c0+3)*3], pw31=sp2w[(c0+3)*3+1], pw32=sp2w[(c0+3)*3+2], pb3=sp2b[c0+3];
    float4 res = make_float4(0,0,0,0);
    #pragma unroll 4
    for (int n=0; n<16; ++n){
        const int sjn = sjL[base+n];
        float4 v4 = ((const float4*)(vbuf + (size_t)sjn*CH))[t];
        const float rr0 = rrL[base+n][0], rr1 = rrL[base+n][1], rr2 = rrL[base+n][2];
        const float a0 = att[base+n][ho+0], a1 = att[base+n][ho+1];
        const float a2_ = att[base+n][ho+2], a3 = att[base+n][ho+3];
        res.x += a0*(v4.x + rr0*pw00+rr1*pw01+rr2*pw02+pb0);
        res.y += a1*(v4.y + rr0*pw10+rr1*pw11+rr2*pw12+pb1);
        res.z += a2_*(v4.z + rr0*pw20+rr1*pw21+rr2*pw22+pb2);
        res.w += a3*(v4.w + rr0*pw30+rr1*pw31+rr2*pw32+pb3);
    }
    ((float4*)outbuf)[(size_t)i*16 + t] = res;

    // fused bn2 stats: thread holds channels 4t..4t+3 of point i
    float4 sq = make_float4(res.x*res.x, res.y*res.y, res.z*res.z, res.w*res.w);
    #pragma unroll
    for (int msk=32;msk>=16;msk>>=1){
        res.x+=__shfl_xor(res.x,msk); res.y+=__shfl_xor(res.y,msk);
        res.z+=__shfl_xor(res.z,msk); res.w+=__shfl_xor(res.w,msk);
        sq.x+=__shfl_xor(sq.x,msk);  sq.y+=__shfl_xor(sq.y,msk);
        sq.z+=__shfl_xor(sq.z,msk);  sq.w+=__shfl_xor(sq.w,msk);
    }
    const int wv = tid>>6;
    if ((tid&63) < 16){
        red[wv][t*4+0]=res.x; red[wv][t*4+1]=res.y; red[wv][t*4+2]=res.z; red[wv][t*4+3]=res.w;
        red[wv][64+t*4+0]=sq.x; red[wv][64+t*4+1]=sq.y; red[wv][64+t*4+2]=sq.z; red[wv][64+t*4+3]=sq.w;
    }
    __syncthreads();
    if (tid < 128) {
        float tt = red[0][tid]+red[1][tid]+red[2][tid]+red[3][tid];
        atomicAdd(&gstat[(blockIdx.x & (NREP-1))*128 + tid], tt);
    }
}

// ---------- final = relu(bn3(h3) + x_skip) ----------
__global__ __launch_bounds__(256) void k_final(
    const float* __restrict__ h3, const float* __restrict__ x,
    const float* __restrict__ bnrep, const float* __restrict__ g,
    const float* __restrict__ b, float* __restrict__ out)
{
    __shared__ float s_tmp[128];
    __shared__ float sc[64], sh[64];
    const int tid = threadIdx.x;
    LOAD_SCSH(bnrep, 1.f/NPTS, g, b, sc, sh, 64);
    const int gi = blockIdx.x*256 + tid;
    const int c0 = (gi & 15)*4;
    float4 h = ((const float4*)h3)[gi];
    float4 xv = ((const float4*)x)[gi];
    float4 o;
    o.x = fmaxf(h.x*sc[c0+0]+sh[c0+0]+xv.x, 0.f);
    o.y = fmaxf(h.y*sc[c0+1]+sh[c0+1]+xv.y, 0.f);
    o.z = fmaxf(h.z*sc[c0+2]+sh[c0+2]+xv.z, 0.f);
    o.w = fmaxf(h.w*sc[c0+3]+sh[c0+3]+xv.w, 0.f);
    ((float4*)out)[gi] = o;
}

extern "C" void kernel_launch(void* const* d_in, const int* in_sizes, int n_in,
                              void* d_out, int out_size, void* d_ws, size_t ws_size,
                              hipStream_t stream) {
    (void)in_sizes; (void)n_in; (void)out_size; (void)ws_size;
    const float* pos   = (const float*)d_in[0];
    const float* x     = (const float*)d_in[1];
    const float* W1    = (const float*)d_in[2];
    const float* Wk    = (const float*)d_in[3];
    const float* bk    = (const float*)d_in[4];
    const float* Wq    = (const float*)d_in[5];
    const float* bq    = (const float*)d_in[6];
    const float* Wv    = (const float*)d_in[7];
    const float* bv    = (const float*)d_in[8];
    const float* p1w   = (const float*)d_in[9];
    const float* p1b   = (const float*)d_in[10];
    const float* pg    = (const float*)d_in[11];
    const float* pb    = (const float*)d_in[12];
    const float* p2w   = (const float*)d_in[13];
    const float* p2b   = (const float*)d_in[14];
    const float* w1g   = (const float*)d_in[15];
    const float* w1bb  = (const float*)d_in[16];
    const float* w1w   = (const float*)d_in[17];
    const float* w1bias= (const float*)d_in[18];
    const float* w2g   = (const float*)d_in[19];
    const float* w2bb  = (const float*)d_in[20];
    const float* w2w   = (const float*)d_in[21];
    const float* w2bias= (const float*)d_in[22];
    const float* W3    = (const float*)d_in[23];
    const float* bn1g  = (const float*)d_in[24];
    const float* bn1b  = (const float*)d_in[25];
    const float* bn2g  = (const float*)d_in[26];
    const float* bn2b  = (const float*)d_in[27];
    const float* bn3g  = (const float*)d_in[28];
    const float* bn3b  = (const float*)d_in[29];
    const int*   ei    = (const int*)d_in[30];
    float* ws  = (float*)d_ws;
    float* out = (float*)d_out;

    hipMemsetAsync(ws, 0, STATS_FLOATS*sizeof(float), stream);

    // u precompute + p-bn stats (independent of GEMM chain)
    k_pstats_u<<<2048, 256, 0, stream>>>(pos, ei, p1w, p1b,
        (float4*)(ws+OFF_U), ws+G_P);
    // t1 = x @ W1^T + bn1 stats
    k_gemm64<<<512, 256, 0, stream>>>(x, W1, ws+OFF_T1,
        nullptr, nullptr, nullptr, 0, ws+G_BN1);
    // k,q,v
    k_kqv<<<768, 256, 0, stream>>>(ws+OFF_T1, Wk, bk, Wq, bq, Wv, bv,
        ws+G_BN1, bn1g, bn1b, ws+OFF_K, ws+OFF_Q, ws+OFF_V);
    // w_bn1 stats
    k_edge1<<<2048, 256, 0, stream>>>(ei, (const float4*)(ws+OFF_U),
        ws+OFF_K, ws+OFF_Q, ws+G_P, pg, pb, p2w, p2b, ws+G_W1);
    // a2 + w_bn2 stats
    k_edge2<<<2048, 256, 0, stream>>>(ei, (const float4*)(ws+OFF_U),
        ws+OFF_K, ws+OFF_Q, ws+G_P, pg, pb, p2w, p2b,
        ws+G_W1, w1g, w1bb, w1w, w1bias, ws+OFF_A2, ws+G_W2);
    // softmax + aggregate + bn2 stats
    k_attn<<<2048, 256, 0, stream>>>(ei, (const float4*)(ws+OFF_U),
        ws+OFF_V, ws+OFF_A2, ws+G_P, pg, pb, p2w, p2b,
        ws+G_W2, w2g, w2bb, w2w, w2bias, ws+OFF_OUT, ws+G_BN2);
    // h3 = relu(bn2(out)) @ W3^T + bn3 stats
    k_gemm64<<<512, 256, 0, stream>>>(ws+OFF_OUT, W3, ws+OFF_H3,
        ws+G_BN2, bn2g, bn2b, 1, ws+G_BN3);
    // final
    k_final<<<2048, 256, 0, stream>>>(ws+OFF_H3, x, ws+G_BN3, bn3g, bn3b, out);
}